// Round 13
// baseline (2943.040 us; speedup 1.0000x reference)
//
#include <hip/hip_runtime.h>

// Problem dims (fixed)
#define BATCH 32
#define SEQ   512
#define DMOD  1024
#define DFFN  4096
#define NHEAD 16
#define DHEAD 64
#define NLAY  4
#define NTOK  (BATCH * SEQ)   // 16384

typedef __attribute__((ext_vector_type(8))) short short8;
typedef __attribute__((ext_vector_type(4))) float f32x4;
typedef unsigned int uint32;

__device__ __forceinline__ unsigned short f2bf(float f) {
  uint32 u = __builtin_bit_cast(uint32, f);
  u += 0x7fffu + ((u >> 16) & 1u);             // RNE
  return (unsigned short)(u >> 16);
}
__device__ __forceinline__ float gelu_f(float x) {
  float u = 0.7978845608028654f * (x + 0.044715f * x * x * x);
  u = fminf(fmaxf(u, -15.f), 15.f);
  float e = __expf(2.f * u);
  return 0.5f * x * (1.f + (e - 1.f) / (e + 1.f));
}

#define GLOAD16(g, l) __builtin_amdgcn_global_load_lds( \
    (const __attribute__((address_space(1))) void*)(g), \
    (__attribute__((address_space(3))) void*)(l), 16, 0, 0)

#define MFMA16(a, b, c) __builtin_amdgcn_mfma_f32_16x16x32_bf16((a), (b), (c), 0, 0, 0)

// ---------------- positional encoding table: pe[l][d], 512x1024 ----------------
__global__ __launch_bounds__(256) void pe_kernel(float* __restrict__ pe) {
  const int idx = blockIdx.x * 256 + threadIdx.x;   // 0 .. 512*512-1 (pairs)
  const int l = idx >> 9;
  const int i = idx & 511;
  const float dv = __expf((float)(2 * i) * (-9.210340371976184f / (float)DMOD));
  const float a = (float)l * dv;
  pe[(size_t)l * DMOD + 2 * i]     = sinf(a);
  pe[(size_t)l * DMOD + 2 * i + 1] = cosf(a);
}

// ---------------- x + pe + speaker -> (optional f32) + bf16 ----------------
__global__ __launch_bounds__(256) void prep_kernel(
    const float* __restrict__ x, const float* __restrict__ pe, const float* __restrict__ spk,
    float* __restrict__ of32, unsigned short* __restrict__ o16)
{
  const size_t id4 = (size_t)blockIdx.x * 256 + threadIdx.x;  // over B*L*D/4
  const size_t e = id4 * 4;
  const int b  = (int)(e >> 19);
  const int ld = (int)(e & ((1u << 19) - 1));
  const int d  = (int)(e & 1023);
  float4 xv = ((const float4*)x)[id4];
  float4 pv = ((const float4*)pe)[ld >> 2];
  float4 sv = ((const float4*)spk)[(size_t)b * 256 + (d >> 2)];
  float4 o;
  o.x = xv.x + pv.x + sv.x;
  o.y = xv.y + pv.y + sv.y;
  o.z = xv.z + pv.z + sv.z;
  o.w = xv.w + pv.w + sv.w;
  if (of32) ((float4*)of32)[id4] = o;
  ushort4 h;
  h.x = f2bf(o.x); h.y = f2bf(o.y); h.z = f2bf(o.z); h.w = f2bf(o.w);
  ((ushort4*)o16)[id4] = h;
}

// ---------------- merged per-layer weight transpose: all 6 weights ----------------
__global__ __launch_bounds__(256) void wtrans_all(
    const float* __restrict__ Wq, const float* __restrict__ Wk,
    const float* __restrict__ Wv, const float* __restrict__ Wo,
    const float* __restrict__ W1, const float* __restrict__ W2, int layer,
    unsigned short* __restrict__ Wqt, unsigned short* __restrict__ Wkt,
    unsigned short* __restrict__ Wvt, unsigned short* __restrict__ Wot,
    unsigned short* __restrict__ W1t, unsigned short* __restrict__ W2t)
{
  __shared__ float tile[64][65];
  const int bid = blockIdx.x;
  const float* W; unsigned short* Wt; int K, N, bx, by;
  if (bid < 1024) {
    const int which = bid >> 8, r = bid & 255;
    bx = r & 15; by = r >> 4; K = DMOD; N = DMOD;
    const size_t off = (size_t)layer * DMOD * DMOD;
    W  = (which == 0 ? Wq : which == 1 ? Wk : which == 2 ? Wv : Wo) + off;
    Wt = (which == 0 ? Wqt : which == 1 ? Wkt : which == 2 ? Wvt : Wot);
  } else if (bid < 2048) {
    const int r = bid - 1024;
    bx = r & 63; by = r >> 6; K = DMOD; N = DFFN;
    W = W1 + (size_t)layer * DMOD * DFFN; Wt = W1t;
  } else {
    const int r = bid - 2048;
    bx = r & 15; by = r >> 4; K = DFFN; N = DMOD;
    W = W2 + (size_t)layer * DMOD * DFFN; Wt = W2t;
  }
  const int n0 = bx * 64, k0 = by * 64;
  const int tx = threadIdx.x & 63, ty = threadIdx.x >> 6;
  #pragma unroll
  for (int i = 0; i < 16; i++) {
    int r = ty + 4 * i;
    tile[r][tx] = W[(size_t)(k0 + r) * N + n0 + tx];
  }
  __syncthreads();
  #pragma unroll
  for (int i = 0; i < 16; i++) {
    int rn = ty + 4 * i;
    Wt[(size_t)(n0 + rn) * K + k0 + tx] = f2bf(tile[tx][rn]);
  }
}

// ---------------- LayerNorm: one block per row (1024 cols) ----------------
template<int WRITE_F32>
__global__ __launch_bounds__(256) void ln_kernel(
    const float* __restrict__ x, const float* __restrict__ g, const float* __restrict__ bta,
    float* __restrict__ of32, unsigned short* __restrict__ o16)
{
  const int row = blockIdx.x;
  const int t = threadIdx.x;
  const float4 v = ((const float4*)(x + (size_t)row * DMOD))[t];
  float s  = v.x + v.y + v.z + v.w;
  float s2 = v.x*v.x + v.y*v.y + v.z*v.z + v.w*v.w;
  #pragma unroll
  for (int off = 32; off > 0; off >>= 1) {
    s  += __shfl_down(s, off);
    s2 += __shfl_down(s2, off);
  }
  __shared__ float red[8];
  if ((t & 63) == 0) { red[(t >> 6) * 2] = s; red[(t >> 6) * 2 + 1] = s2; }
  __syncthreads();
  const float sum  = red[0] + red[2] + red[4] + red[6];
  const float sum2 = red[1] + red[3] + red[5] + red[7];
  const float mean = sum * (1.f / (float)DMOD);
  const float var  = sum2 * (1.f / (float)DMOD) - mean * mean;
  const float rstd = rsqrtf(var + 1e-6f);
  const float4 gg = ((const float4*)g)[t];
  const float4 bb = ((const float4*)bta)[t];
  float4 o;
  o.x = (v.x - mean) * rstd * gg.x + bb.x;
  o.y = (v.y - mean) * rstd * gg.y + bb.y;
  o.z = (v.z - mean) * rstd * gg.z + bb.z;
  o.w = (v.w - mean) * rstd * gg.w + bb.w;
  if (WRITE_F32) ((float4*)of32)[(size_t)row * 256 + t] = o;
  ushort4 h;
  h.x = f2bf(o.x); h.y = f2bf(o.y); h.z = f2bf(o.z); h.w = f2bf(o.w);
  ((ushort4*)o16)[(size_t)row * 256 + t] = h;
}

// ---------------- GEMM 128x256, 8 waves, BK=32 DOUBLE-BUFFERED (T3-minimum) ------
// Per K-tile: issue stage(kt+1, buf^1) BEFORE computing buf, ONE barrier per tile
// (drains vmcnt after a full MFMA phase has covered the load latency). 2x24 KB
// LDS = 48 KB -> 2 blocks/CU at (512,4). Round-10 proven addressing/swizzle
// (c ^ ((row>>1)&3), 64B rows, 0 conflicts). Round-9 lesson: min-waves stays 4.
// MODE 0: fused QKV via grid.z: z=0 Q (bias,*0.125,bf16), z=1 K (bias,bf16),
//         z=2 V (bias, bf16 V^T [b][ch][l]).  A = z?A1:A0.
// MODE 1: bias+gelu->bf16 (W1).  MODE 2: bias+res->f32.  MODE 3: bias+inplace->f32.
template<int MODE>
__global__ __launch_bounds__(512, 4) void gemm128(
    const unsigned short* __restrict__ A0, const unsigned short* __restrict__ A1,
    const unsigned short* __restrict__ B0, const unsigned short* __restrict__ B1,
    const unsigned short* __restrict__ B2,
    const float* __restrict__ bias0, const float* __restrict__ bias1,
    const float* __restrict__ bias2, const float* __restrict__ res,
    void* out0, void* out1, void* out2, int N, int K)
{
  __shared__ unsigned short Sh[2][12288];  // 2 bufs x 24 KB: A[0,4096) B[4096,12288)
  const int t = threadIdx.x;
  const int lane = t & 63, w = t >> 6;
  const int wm = w >> 2, wn = w & 3;       // 2(M) x 4(N) wave grid; wave owns 64x64
  const int g = lane >> 4, rm = lane & 15;

  // XCD-aware bijective remap over the whole (possibly 3D) grid
  const int gx = gridDim.x, gy = gridDim.y;
  const int nwg = gx * gy * gridDim.z;
  const int hid = (blockIdx.z * gy + blockIdx.y) * gx + blockIdx.x;
  const int wid = (hid & 7) * (nwg >> 3) + (hid >> 3);
  const int bx = wid % gx;
  const int rest = wid / gx;
  const int by = rest % gy;
  const int z  = rest / gy;                // 0 for 2D grids

  const unsigned short* A  = (MODE == 0 && z) ? A1 : A0;
  const unsigned short* Bt = (MODE == 0) ? (z == 0 ? B0 : z == 1 ? B1 : B2) : B0;
  const float* bias        = (MODE == 0) ? (z == 0 ? bias0 : z == 1 ? bias1 : bias2) : bias0;
  void* outp               = (MODE == 0) ? (z == 0 ? out0 : z == 1 ? out1 : out2) : out0;

  const size_t tm = (size_t)by * 128;
  const size_t tn = (size_t)bx * 256;

  // staging (round-10 proven): A 512 chunks (1/thread), B 1024 (2/thread);
  // source pre-swizzled c ^ ((row>>1)&3); LDS dest linear.
  const int i0 = t, i1 = 512 + t;
  const int ra  = i0 >> 2;
  const int ca  = 8 * ((i0 & 3) ^ ((ra >> 1) & 3));
  const int rb1 = i1 >> 2;
  const int cb1 = 8 * ((i1 & 3) ^ ((rb1 >> 1) & 3));
  const unsigned short* Abase  = A  + (tm + ra) * (size_t)K + ca;
  const unsigned short* Bbase0 = Bt + (tn + ra) * (size_t)K + ca;
  const unsigned short* Bbase1 = Bt + (tn + rb1) * (size_t)K + cb1;

  // swizzled fragment read offsets (bytes) — k-invariant
  int aoff[4], boff[4];
  #pragma unroll
  for (int fm = 0; fm < 4; fm++) {
    const int r = wm * 64 + fm * 16 + rm;
    aoff[fm] = r * 64 + ((g * 16) ^ (((r >> 1) & 3) << 4));
  }
  #pragma unroll
  for (int fn = 0; fn < 4; fn++) {
    const int r = wn * 64 + fn * 16 + rm;
    boff[fn] = r * 64 + ((g * 16) ^ (((r >> 1) & 3) << 4));
  }

  f32x4 acc[4][4];
  #pragma unroll
  for (int i = 0; i < 4; i++)
    #pragma unroll
    for (int j = 0; j < 4; j++)
      acc[i][j] = (f32x4){0.f, 0.f, 0.f, 0.f};

  const int nt = K >> 5;
  // prologue: tile 0 into buf 0
  {
    GLOAD16(Abase,      &Sh[0][i0 * 8]);
    GLOAD16(Bbase0,     &Sh[0][4096 + i0 * 8]);
    GLOAD16(Bbase1,     &Sh[0][4096 + i1 * 8]);
  }
  __syncthreads();

  int buf = 0;
  for (int kt = 0; kt < nt; kt++) {
    if (kt + 1 < nt) {
      const int k0 = (kt + 1) * 32;
      GLOAD16(Abase + k0,  &Sh[buf ^ 1][i0 * 8]);
      GLOAD16(Bbase0 + k0, &Sh[buf ^ 1][4096 + i0 * 8]);
      GLOAD16(Bbase1 + k0, &Sh[buf ^ 1][4096 + i1 * 8]);
    }
    const char* As = (const char*)&Sh[buf][0];
    const char* Bs = (const char*)&Sh[buf][4096];
    short8 a[4], b[4];
    #pragma unroll
    for (int fm = 0; fm < 4; fm++) a[fm] = *(const short8*)(As + aoff[fm]);
    #pragma unroll
    for (int fn = 0; fn < 4; fn++) b[fn] = *(const short8*)(Bs + boff[fn]);
    #pragma unroll
    for (int fm = 0; fm < 4; fm++)
      #pragma unroll
      for (int fn = 0; fn < 4; fn++)
        acc[fm][fn] = MFMA16(a[fm], b[fn], acc[fm][fn]);
    __syncthreads();    // one barrier/tile: drains t+1 loads (latency covered) +
    buf ^= 1;           // orders reads-of-buf before next overwrite
  }

  // ---------------- epilogue (round-10/12 proven) ----------------
  if (MODE == 2 || MODE == 3) {
    #pragma unroll
    for (int fn = 0; fn < 4; fn++) {
      const size_t gcol = tn + wn * 64 + fn * 16 + rm;
      const float bc = bias[gcol];
      #pragma unroll
      for (int fm = 0; fm < 4; fm++) {
        #pragma unroll
        for (int r = 0; r < 4; r++) {
          const size_t grow = tm + wm * 64 + fm * 16 + g * 4 + r;
          const size_t off = grow * (size_t)N + gcol;
          float v = acc[fm][fn][r] + bc;
          if (MODE == 2) ((float*)outp)[off] = v + res[off];
          else { float* op = (float*)outp; op[off] = v + op[off]; }
        }
      }
    }
  } else if (MODE == 0) {
    for (int half = 0; half < 2; half++) {
      __syncthreads();
      if ((w >> 2) == half) {
        unsigned short* eb = &Sh[0][0] + (w & 3) * 4096;
        if (z == 2) {
          // V^T slab [64 ch][64 tok]
          #pragma unroll
          for (int fn = 0; fn < 4; fn++) {
            const float bc = bias[tn + wn * 64 + fn * 16 + rm];
            #pragma unroll
            for (int fm = 0; fm < 4; fm++)
              #pragma unroll
              for (int r = 0; r < 4; r++) {
                const int tok = fm * 16 + g * 4 + r;
                const int ch  = fn * 16 + rm;
                eb[ch * 64 + (tok ^ ((ch & 7) << 3))] = f2bf(acc[fm][fn][r] + bc);
              }
          }
          const int tok0 = (int)tm + wm * 64;
          const int bb = tok0 >> 9, l0 = tok0 & 511;
          #pragma unroll
          for (int pass = 0; pass < 8; pass++) {
            const int ch = pass * 8 + (lane >> 3);
            const int t8 = (lane & 7) * 8;
            short8 vv = *(const short8*)&eb[ch * 64 + (t8 ^ ((ch & 7) << 3))];
            *(short8*)((unsigned short*)outp +
                       ((size_t)bb * 1024 + tn + wn * 64 + ch) * 512 + l0 + t8) = vv;
          }
        } else {
          // row-major slab [64 rows][64 cols]
          #pragma unroll
          for (int fn = 0; fn < 4; fn++) {
            const float bc = bias[tn + wn * 64 + fn * 16 + rm];
            #pragma unroll
            for (int fm = 0; fm < 4; fm++)
              #pragma unroll
              for (int r = 0; r < 4; r++) {
                float v = acc[fm][fn][r] + bc;
                if (z == 0) v *= 0.125f;
                const int lr = fm * 16 + g * 4 + r;
                const int lc = fn * 16 + rm;
                eb[lr * 64 + (lc ^ (g << 4))] = f2bf(v);
              }
          }
          #pragma unroll
          for (int pass = 0; pass < 8; pass++) {
            const int lr = pass * 8 + (lane >> 3);
            const int lc8 = (lane & 7) * 8;
            const int q = (lr >> 2) & 3;
            short8 vv = *(const short8*)&eb[lr * 64 + (lc8 ^ (q << 4))];
            *(short8*)((unsigned short*)outp +
                       (tm + wm * 64 + lr) * (size_t)N + tn + wn * 64 + lc8) = vv;
          }
        }
      }
    }
  } else {
    for (int half = 0; half < 2; half++) {
      __syncthreads();
      if ((w >> 2) == half) {
        unsigned short* eb = &Sh[0][0] + (w & 3) * 4096;
        #pragma unroll
        for (int fn = 0; fn < 4; fn++) {
          const float bc = bias[tn + wn * 64 + fn * 16 + rm];
          #pragma unroll
          for (int fm = 0; fm < 4; fm++)
            #pragma unroll
            for (int r = 0; r < 4; r++) {
              const int lr = fm * 16 + g * 4 + r;
              const int lc = fn * 16 + rm;
              eb[lr * 64 + (lc ^ (g << 4))] = f2bf(gelu_f(acc[fm][fn][r] + bc));
            }
        }
        #pragma unroll
        for (int pass = 0; pass < 8; pass++) {
          const int lr = pass * 8 + (lane >> 3);
          const int lc8 = (lane & 7) * 8;
          const int q = (lr >> 2) & 3;
          short8 vv = *(const short8*)&eb[lr * 64 + (lc8 ^ (q << 4))];
          *(short8*)((unsigned short*)outp +
                     (tm + wm * 64 + lr) * (size_t)N + tn + wn * 64 + lc8) = vv;
        }
      }
    }
  }
}

// ---------------- MFMA flash attention: defer-max (T13) + deferred l-reduce -----
__global__ __launch_bounds__(256) void attn_mfma(
    const unsigned short* __restrict__ qb, const unsigned short* __restrict__ kb,
    const unsigned short* __restrict__ vt, unsigned short* __restrict__ ctx)
{
  __shared__ unsigned short Qs[128 * 64];      // 16 KB
  __shared__ unsigned short Ks[2][32 * 64];    //  8 KB
  __shared__ unsigned short Vs[2][64 * 32];    //  8 KB
  __shared__ unsigned short Ps[4][32 * 40];    // 10 KB
  const int t = threadIdx.x;
  const int lane = t & 63, w = t >> 6;
  const int g = lane >> 4, rm = lane & 15;
  const int qt = blockIdx.x, h = blockIdx.y, b = blockIdx.z;

  const unsigned short* qg = qb + ((size_t)(b * SEQ + qt * 128)) * DMOD + h * DHEAD;
  const unsigned short* kg = kb + ((size_t)(b * SEQ)) * DMOD + h * DHEAD;
  const unsigned short* vg = vt + ((size_t)(b * NHEAD + h)) * DHEAD * SEQ;  // [64][512]

  #pragma unroll
  for (int ii = 0; ii < 4; ii++) {
    const int i = ii * 256 + t;
    const int r = i >> 3, c = i & 7;
    const int bc = 16 * (c ^ (r & 7));
    GLOAD16(qg + (size_t)r * DMOD + (bc >> 1), Qs + (size_t)(ii * 256 + w * 64) * 8);
  }
  __syncthreads();

  short8 aq[2][2];
  #pragma unroll
  for (int fq = 0; fq < 2; fq++)
    #pragma unroll
    for (int kd = 0; kd < 2; kd++) {
      const int r = w * 32 + fq * 16 + rm;
      aq[fq][kd] = *(const short8*)((const char*)Qs + r * 128 + ((kd * 64 + g * 16) ^ ((r & 7) << 4)));
    }

  float mrow[2][4], lsum[2][4];
  f32x4 of[2][4];
  #pragma unroll
  for (int fq = 0; fq < 2; fq++) {
    #pragma unroll
    for (int j = 0; j < 4; j++) { mrow[fq][j] = -INFINITY; lsum[fq][j] = 0.f; }
    #pragma unroll
    for (int fd = 0; fd < 4; fd++) of[fq][fd] = (f32x4){0.f, 0.f, 0.f, 0.f};
  }

  auto stageK = [&](int kt, int bf) {
    const int r = t >> 3, c = t & 7;
    const int bc = 16 * (c ^ (r & 7));
    GLOAD16(kg + (size_t)(kt * 32 + r) * DMOD + (bc >> 1), Ks[bf] + (size_t)w * 512);
  };
  auto stageV = [&](int kt, int bf) {
    const int r = t >> 2, c = t & 3;
    const int bc = 16 * (c ^ (r & 3));
    GLOAD16(vg + (size_t)r * SEQ + kt * 32 + (bc >> 1), Vs[bf] + (size_t)w * 512);
  };

  stageK(0, 0); stageV(0, 0);
  __syncthreads();
  int buf = 0;

  for (int kt = 0; kt < SEQ / 32; kt++) {
    if (kt + 1 < SEQ / 32) { stageK(kt + 1, buf ^ 1); stageV(kt + 1, buf ^ 1); }

    f32x4 s[2][2];
    #pragma unroll
    for (int fq = 0; fq < 2; fq++)
      #pragma unroll
      for (int fk = 0; fk < 2; fk++) {
        f32x4 a = (f32x4){0.f, 0.f, 0.f, 0.f};
        #pragma unroll
        for (int kd = 0; kd < 2; kd++) {
          const int r = fk * 16 + rm;
          short8 bk = *(const short8*)((const char*)Ks[buf] + r * 128 + ((kd * 64 + g * 16) ^ ((r & 7) << 4)));
          a = MFMA16(aq[fq][kd], bk, a);
        }
        s[fq][fk] = a;
      }

    // tile row-max + defer-max gate
    float pm[2][4];
    int grow = 0;
    #pragma unroll
    for (int fq = 0; fq < 2; fq++)
      #pragma unroll
      for (int j = 0; j < 4; j++) {
        float mx = fmaxf(s[fq][0][j], s[fq][1][j]);
        #pragma unroll
        for (int mk = 1; mk < 16; mk <<= 1) mx = fmaxf(mx, __shfl_xor(mx, mk));
        pm[fq][j] = mx;
        grow |= (mx > mrow[fq][j] + 8.f);
      }
    if (__any(grow)) {
      #pragma unroll
      for (int fq = 0; fq < 2; fq++)
        #pragma unroll
        for (int j = 0; j < 4; j++) {
          const float mn = fmaxf(mrow[fq][j], pm[fq][j]);
          const float corr = __expf(mrow[fq][j] - mn);
          mrow[fq][j] = mn;
          lsum[fq][j] *= corr;
          #pragma unroll
          for (int fd = 0; fd < 4; fd++) of[fq][fd][j] *= corr;
        }
    }
    #pragma unroll
    for (int fq = 0; fq < 2; fq++)
      #pragma unroll
      for (int j = 0; j < 4; j++) {
        const float p0 = __expf(s[fq][0][j] - mrow[fq][j]);
        const float p1 = __expf(s[fq][1][j] - mrow[fq][j]);
        lsum[fq][j] += p0 + p1;
        Ps[w][(fq * 16 + g * 4 + j) * 40 + rm]      = f2bf(p0);
        Ps[w][(fq * 16 + g * 4 + j) * 40 + 16 + rm] = f2bf(p1);
      }

    #pragma unroll
    for (int fq = 0; fq < 2; fq++) {
      const short8 pa = *(const short8*)((const char*)Ps[w] + (fq * 16 + rm) * 80 + g * 16);
      #pragma unroll
      for (int fd = 0; fd < 4; fd++) {
        const int r = fd * 16 + rm;
        const short8 vb = *(const short8*)((const char*)Vs[buf] + r * 64 + ((g * 16) ^ ((r & 3) << 4)));
        of[fq][fd] = MFMA16(pa, vb, of[fq][fd]);
      }
    }

    __syncthreads();
    buf ^= 1;
  }

  // deferred 16-lane l reduction, then normalize + store
  #pragma unroll
  for (int fq = 0; fq < 2; fq++)
    #pragma unroll
    for (int j = 0; j < 4; j++) {
      float ls = lsum[fq][j];
      #pragma unroll
      for (int mk = 1; mk < 16; mk <<= 1) ls += __shfl_xor(ls, mk);
      const float inv = 1.f / ls;
      const size_t q = (size_t)b * SEQ + qt * 128 + w * 32 + fq * 16 + g * 4 + j;
      #pragma unroll
      for (int fd = 0; fd < 4; fd++)
        ctx[q * DMOD + h * DHEAD + fd * 16 + rm] = f2bf(of[fq][fd][j] * inv);
    }
}

extern "C" void kernel_launch(void* const* d_in, const int* in_sizes, int n_in,
                              void* d_out, int out_size, void* d_ws, size_t ws_size,
                              hipStream_t stream) {
  const float* x_a   = (const float*)d_in[0];
  const float* x_b   = (const float*)d_in[1];
  const float* spk   = (const float*)d_in[2];
  const float* Wq    = (const float*)d_in[3];
  const float* bq    = (const float*)d_in[4];
  const float* Wk    = (const float*)d_in[5];
  const float* bk    = (const float*)d_in[6];
  const float* Wv    = (const float*)d_in[7];
  const float* bv    = (const float*)d_in[8];
  const float* Wo    = (const float*)d_in[9];
  const float* bo    = (const float*)d_in[10];
  const float* ln_g  = (const float*)d_in[11];
  const float* ln_b  = (const float*)d_in[12];
  const float* fln_g = (const float*)d_in[13];
  const float* fln_b = (const float*)d_in[14];
  const float* W1    = (const float*)d_in[15];
  const float* b1    = (const float*)d_in[16];
  const float* W2    = (const float*)d_in[17];
  const float* b2    = (const float*)d_in[18];
  float* out = (float*)d_out;           // also serves as the f32 x_b master (X)

  char* ws = (char*)d_ws;
  size_t o = 0;
  auto give = [&](size_t bytes) { char* p = ws + o; o += (bytes + 255) & ~(size_t)255; return p; };
  const size_t ACT2 = (size_t)NTOK * DMOD * 2;   // 32 MB bf16 activation

  unsigned short* qb16  = (unsigned short*)give(ACT2);
  unsigned short* kb16  = (unsigned short*)give(ACT2);
  unsigned short* vt16  = (unsigned short*)give(ACT2);       // V^T [b][h][d][l]
  unsigned short* ctx16 = (unsigned short*)give(ACT2);
  unsigned short* xa16  = (unsigned short*)give(ACT2);
  unsigned short* xbn16 = (unsigned short*)give(ACT2);
  float*          outf  = (float*)give((size_t)NTOK * DMOD * 4);   // 64 MB (residual stream)
  unsigned short* Wqt   = (unsigned short*)give((size_t)DMOD * DMOD * 2);
  unsigned short* Wkt   = (unsigned short*)give((size_t)DMOD * DMOD * 2);
  unsigned short* Wvt   = (unsigned short*)give((size_t)DMOD * DMOD * 2);
  unsigned short* Wot   = (unsigned short*)give((size_t)DMOD * DMOD * 2);
  unsigned short* W1t   = (unsigned short*)give((size_t)DMOD * DFFN * 2);
  unsigned short* W2t   = (unsigned short*)give((size_t)DMOD * DFFN * 2);
  float*          peb   = (float*)give((size_t)SEQ * DMOD * 4);
  unsigned short* inter = qb16;     // 128 MB span over qb16..ctx16 (dead during FFN)
  (void)ws_size; (void)in_sizes; (void)n_in; (void)out_size;

  const dim3 blk(256);
  const dim3 blk512(512);

  pe_kernel<<<dim3((SEQ * (DMOD / 2)) / 256), blk, 0, stream>>>(peb);
  const int nprep = (NTOK * DMOD / 4) / 256;
  prep_kernel<<<dim3(nprep), blk, 0, stream>>>(x_a, peb, spk, nullptr, xa16);
  prep_kernel<<<dim3(nprep), blk, 0, stream>>>(x_b, peb, spk, out, xbn16);

  const dim3 gQKV(DMOD / 256, NTOK / 128, 3);   // (4,128,3) = 1536 blocks
  const dim3 gWO (DMOD / 256, NTOK / 128);      // (4,128)   = 512
  const dim3 gW1 (DFFN / 256, NTOK / 128);      // (16,128)  = 2048
  const dim3 gW2 (DMOD / 256, NTOK / 128);      // (4,128)   = 512

  for (int i = 0; i < NLAY; i++) {
    wtrans_all<<<dim3(3072), blk, 0, stream>>>(Wq, Wk, Wv, Wo, W1, W2, i,
                                               Wqt, Wkt, Wvt, Wot, W1t, W2t);
    if (i != 0) {
      ln_kernel<1><<<dim3(NTOK), blk, 0, stream>>>(out, ln_g + (size_t)i * DMOD, ln_b + (size_t)i * DMOD, outf, xbn16);
    }
    gemm128<0><<<gQKV, blk512, 0, stream>>>(
        xbn16, xa16, Wqt, Wkt, Wvt,
        bq + (size_t)i * DMOD, bk + (size_t)i * DMOD, bv + (size_t)i * DMOD,
        nullptr, qb16, kb16, vt16, DMOD, DMOD);
    attn_mfma<<<dim3(SEQ / 128, NHEAD, BATCH), blk, 0, stream>>>(qb16, kb16, vt16, ctx16);
    if (i == 0) {
      gemm128<2><<<gWO, blk512, 0, stream>>>(
          ctx16, nullptr, Wot, nullptr, nullptr,
          bo + (size_t)i * DMOD, nullptr, nullptr, out, outf, nullptr, nullptr, DMOD, DMOD);
    } else {
      gemm128<3><<<gWO, blk512, 0, stream>>>(
          ctx16, nullptr, Wot, nullptr, nullptr,
          bo + (size_t)i * DMOD, nullptr, nullptr, nullptr, outf, nullptr, nullptr, DMOD, DMOD);
    }
    ln_kernel<0><<<dim3(NTOK), blk, 0, stream>>>(outf, fln_g + (size_t)i * DMOD, fln_b + (size_t)i * DMOD, nullptr, xbn16);
    gemm128<1><<<gW1, blk512, 0, stream>>>(
        xbn16, nullptr, W1t, nullptr, nullptr,
        b1 + (size_t)i * DFFN, nullptr, nullptr, nullptr, inter, nullptr, nullptr, DFFN, DMOD);
    gemm128<2><<<gW2, blk512, 0, stream>>>(
        inter, nullptr, W2t, nullptr, nullptr,
        b2 + (size_t)i * DMOD, nullptr, nullptr, outf, out, nullptr, nullptr, DMOD, DFFN);
  }
}

// Round 14
// 2713.012 us; speedup vs baseline: 1.0848x; 1.0848x over previous
//
#include <hip/hip_runtime.h>

// Problem dims (fixed)
#define BATCH 32
#define SEQ   512
#define DMOD  1024
#define DFFN  4096
#define NHEAD 16
#define DHEAD 64
#define NLAY  4
#define NTOK  (BATCH * SEQ)   // 16384

typedef __attribute__((ext_vector_type(8))) short short8;
typedef __attribute__((ext_vector_type(4))) float f32x4;
typedef unsigned int uint32;

__device__ __forceinline__ unsigned short f2bf(float f) {
  uint32 u = __builtin_bit_cast(uint32, f);
  u += 0x7fffu + ((u >> 16) & 1u);             // RNE
  return (unsigned short)(u >> 16);
}
__device__ __forceinline__ float gelu_f(float x) {
  float u = 0.7978845608028654f * (x + 0.044715f * x * x * x);
  u = fminf(fmaxf(u, -15.f), 15.f);
  float e = __expf(2.f * u);
  return 0.5f * x * (1.f + (e - 1.f) / (e + 1.f));
}

#define GLOAD16(g, l) __builtin_amdgcn_global_load_lds( \
    (const __attribute__((address_space(1))) void*)(g), \
    (__attribute__((address_space(3))) void*)(l), 16, 0, 0)

#define MFMA16(a, b, c) __builtin_amdgcn_mfma_f32_16x16x32_bf16((a), (b), (c), 0, 0, 0)

// ---------------- positional encoding table: pe[l][d], 512x1024 ----------------
__global__ __launch_bounds__(256) void pe_kernel(float* __restrict__ pe) {
  const int idx = blockIdx.x * 256 + threadIdx.x;   // 0 .. 512*512-1 (pairs)
  const int l = idx >> 9;
  const int i = idx & 511;
  const float dv = __expf((float)(2 * i) * (-9.210340371976184f / (float)DMOD));
  const float a = (float)l * dv;
  pe[(size_t)l * DMOD + 2 * i]     = sinf(a);
  pe[(size_t)l * DMOD + 2 * i + 1] = cosf(a);
}

// ---------------- x + pe + speaker -> (optional f32) + bf16 ----------------
__global__ __launch_bounds__(256) void prep_kernel(
    const float* __restrict__ x, const float* __restrict__ pe, const float* __restrict__ spk,
    float* __restrict__ of32, unsigned short* __restrict__ o16)
{
  const size_t id4 = (size_t)blockIdx.x * 256 + threadIdx.x;  // over B*L*D/4
  const size_t e = id4 * 4;
  const int b  = (int)(e >> 19);
  const int ld = (int)(e & ((1u << 19) - 1));
  const int d  = (int)(e & 1023);
  float4 xv = ((const float4*)x)[id4];
  float4 pv = ((const float4*)pe)[ld >> 2];
  float4 sv = ((const float4*)spk)[(size_t)b * 256 + (d >> 2)];
  float4 o;
  o.x = xv.x + pv.x + sv.x;
  o.y = xv.y + pv.y + sv.y;
  o.z = xv.z + pv.z + sv.z;
  o.w = xv.w + pv.w + sv.w;
  if (of32) ((float4*)of32)[id4] = o;
  ushort4 h;
  h.x = f2bf(o.x); h.y = f2bf(o.y); h.z = f2bf(o.z); h.w = f2bf(o.w);
  ((ushort4*)o16)[id4] = h;
}

// ---------------- merged per-layer weight transpose: all 6 weights ----------------
__global__ __launch_bounds__(256) void wtrans_all(
    const float* __restrict__ Wq, const float* __restrict__ Wk,
    const float* __restrict__ Wv, const float* __restrict__ Wo,
    const float* __restrict__ W1, const float* __restrict__ W2, int layer,
    unsigned short* __restrict__ Wqt, unsigned short* __restrict__ Wkt,
    unsigned short* __restrict__ Wvt, unsigned short* __restrict__ Wot,
    unsigned short* __restrict__ W1t, unsigned short* __restrict__ W2t)
{
  __shared__ float tile[64][65];
  const int bid = blockIdx.x;
  const float* W; unsigned short* Wt; int K, N, bx, by;
  if (bid < 1024) {
    const int which = bid >> 8, r = bid & 255;
    bx = r & 15; by = r >> 4; K = DMOD; N = DMOD;
    const size_t off = (size_t)layer * DMOD * DMOD;
    W  = (which == 0 ? Wq : which == 1 ? Wk : which == 2 ? Wv : Wo) + off;
    Wt = (which == 0 ? Wqt : which == 1 ? Wkt : which == 2 ? Wvt : Wot);
  } else if (bid < 2048) {
    const int r = bid - 1024;
    bx = r & 63; by = r >> 6; K = DMOD; N = DFFN;
    W = W1 + (size_t)layer * DMOD * DFFN; Wt = W1t;
  } else {
    const int r = bid - 2048;
    bx = r & 15; by = r >> 4; K = DFFN; N = DMOD;
    W = W2 + (size_t)layer * DMOD * DFFN; Wt = W2t;
  }
  const int n0 = bx * 64, k0 = by * 64;
  const int tx = threadIdx.x & 63, ty = threadIdx.x >> 6;
  #pragma unroll
  for (int i = 0; i < 16; i++) {
    int r = ty + 4 * i;
    tile[r][tx] = W[(size_t)(k0 + r) * N + n0 + tx];
  }
  __syncthreads();
  #pragma unroll
  for (int i = 0; i < 16; i++) {
    int rn = ty + 4 * i;
    Wt[(size_t)(n0 + rn) * K + k0 + tx] = f2bf(tile[tx][rn]);
  }
}

// ---------------- LayerNorm: one block per row (1024 cols) ----------------
template<int WRITE_F32>
__global__ __launch_bounds__(256) void ln_kernel(
    const float* __restrict__ x, const float* __restrict__ g, const float* __restrict__ bta,
    float* __restrict__ of32, unsigned short* __restrict__ o16)
{
  const int row = blockIdx.x;
  const int t = threadIdx.x;
  const float4 v = ((const float4*)(x + (size_t)row * DMOD))[t];
  float s  = v.x + v.y + v.z + v.w;
  float s2 = v.x*v.x + v.y*v.y + v.z*v.z + v.w*v.w;
  #pragma unroll
  for (int off = 32; off > 0; off >>= 1) {
    s  += __shfl_down(s, off);
    s2 += __shfl_down(s2, off);
  }
  __shared__ float red[8];
  if ((t & 63) == 0) { red[(t >> 6) * 2] = s; red[(t >> 6) * 2 + 1] = s2; }
  __syncthreads();
  const float sum  = red[0] + red[2] + red[4] + red[6];
  const float sum2 = red[1] + red[3] + red[5] + red[7];
  const float mean = sum * (1.f / (float)DMOD);
  const float var  = sum2 * (1.f / (float)DMOD) - mean * mean;
  const float rstd = rsqrtf(var + 1e-6f);
  const float4 gg = ((const float4*)g)[t];
  const float4 bb = ((const float4*)bta)[t];
  float4 o;
  o.x = (v.x - mean) * rstd * gg.x + bb.x;
  o.y = (v.y - mean) * rstd * gg.y + bb.y;
  o.z = (v.z - mean) * rstd * gg.z + bb.z;
  o.w = (v.w - mean) * rstd * gg.w + bb.w;
  if (WRITE_F32) ((float4*)of32)[(size_t)row * 256 + t] = o;
  ushort4 h;
  h.x = f2bf(o.x); h.y = f2bf(o.y); h.z = f2bf(o.z); h.w = f2bf(o.w);
  ((ushort4*)o16)[(size_t)row * 256 + t] = h;
}

// ---------------- GEMM 128x256, 8 waves, BK=64 single-buffer (ROUND-12 BEST) -----
// 48 KB LDS -> 2 blocks/CU at (512,4); cross-block overlap (m114) hides the
// barrier drain (explicit dbuf regressed, round 13 = m99/m100). Swizzle for
// 128B rows: 16B-chunk idx (3b) ^ (row&7), both sides; 2 lanes/bank-slot = free.
// launch_bounds(512,4): round-9 lesson — never raise min-waves blind.
// MODE 0: fused QKV via grid.z: z=0 Q (bias,*0.125,bf16), z=1 K (bias,bf16),
//         z=2 V (bias, bf16 V^T [b][ch][l]).  A = z?A1:A0.
// MODE 1: bias+gelu->bf16 (W1).  MODE 2: bias+res->f32.  MODE 3: bias+inplace->f32.
template<int MODE>
__global__ __launch_bounds__(512, 4) void gemm128(
    const unsigned short* __restrict__ A0, const unsigned short* __restrict__ A1,
    const unsigned short* __restrict__ B0, const unsigned short* __restrict__ B1,
    const unsigned short* __restrict__ B2,
    const float* __restrict__ bias0, const float* __restrict__ bias1,
    const float* __restrict__ bias2, const float* __restrict__ res,
    void* out0, void* out1, void* out2, int N, int K)
{
  __shared__ unsigned short Sh[24576];   // 48 KB: As[0,8192) Bs[8192,24576); epi reuse
  unsigned short* As = Sh;               // 128 rows x 64 hw (128 B/row)
  unsigned short* Bs = Sh + 8192;        // 256 rows x 64 hw
  const int t = threadIdx.x;
  const int lane = t & 63, w = t >> 6;
  const int wm = w >> 2, wn = w & 3;     // 2(M) x 4(N) wave grid; wave owns 64x64
  const int g = lane >> 4, rm = lane & 15;

  // XCD-aware bijective remap over the whole (possibly 3D) grid
  const int gx = gridDim.x, gy = gridDim.y;
  const int nwg = gx * gy * gridDim.z;
  const int hid = (blockIdx.z * gy + blockIdx.y) * gx + blockIdx.x;
  const int wid = (hid & 7) * (nwg >> 3) + (hid >> 3);
  const int bx = wid % gx;
  const int rest = wid / gx;
  const int by = rest % gy;
  const int z  = rest / gy;              // 0 for 2D grids

  const unsigned short* A  = (MODE == 0 && z) ? A1 : A0;
  const unsigned short* Bt = (MODE == 0) ? (z == 0 ? B0 : z == 1 ? B1 : B2) : B0;
  const float* bias        = (MODE == 0) ? (z == 0 ? bias0 : z == 1 ? bias1 : bias2) : bias0;
  void* outp               = (MODE == 0) ? (z == 0 ? out0 : z == 1 ? out1 : out2) : out0;

  const size_t tm = (size_t)by * 128;
  const size_t tn = (size_t)bx * 256;

  // staging per K-tile: A 1024 16B-chunks (2/thread), B 2048 (4/thread).
  // chunk row = idx>>3; chunk-in-row (3b) pre-swizzled: ^ (row&7). Dest linear.
  const int ia0 = t, ia1 = 512 + t;
  const int ra0 = ia0 >> 3, ra1 = ia1 >> 3;
  const int ca0 = 8 * ((ia0 & 7) ^ (ra0 & 7));
  const int ca1 = 8 * ((ia1 & 7) ^ (ra1 & 7));
  const int ib0 = t, ib1 = 512 + t, ib2 = 1024 + t, ib3 = 1536 + t;
  const int rb0 = ib0 >> 3, rb1 = ib1 >> 3, rb2 = ib2 >> 3, rb3 = ib3 >> 3;
  const int cb0 = 8 * ((ib0 & 7) ^ (rb0 & 7));
  const int cb1 = 8 * ((ib1 & 7) ^ (rb1 & 7));
  const int cb2 = 8 * ((ib2 & 7) ^ (rb2 & 7));
  const int cb3 = 8 * ((ib3 & 7) ^ (rb3 & 7));
  const unsigned short* Ab0 = A + (tm + ra0) * (size_t)K + ca0;
  const unsigned short* Ab1 = A + (tm + ra1) * (size_t)K + ca1;
  const unsigned short* Bb0 = Bt + (tn + rb0) * (size_t)K + cb0;
  const unsigned short* Bb1 = Bt + (tn + rb1) * (size_t)K + cb1;
  const unsigned short* Bb2 = Bt + (tn + rb2) * (size_t)K + cb2;
  const unsigned short* Bb3 = Bt + (tn + rb3) * (size_t)K + cb3;

  // swizzled fragment read offsets (bytes), kd=0; kd=1 is ^64
  int aoff[4], boff[4];
  #pragma unroll
  for (int fm = 0; fm < 4; fm++) {
    const int r = wm * 64 + fm * 16 + rm;
    aoff[fm] = r * 128 + ((g ^ (r & 7)) * 16);
  }
  #pragma unroll
  for (int fn = 0; fn < 4; fn++) {
    const int r = wn * 64 + fn * 16 + rm;
    boff[fn] = r * 128 + ((g ^ (r & 7)) * 16);
  }

  f32x4 acc[4][4];
  #pragma unroll
  for (int i = 0; i < 4; i++)
    #pragma unroll
    for (int j = 0; j < 4; j++)
      acc[i][j] = (f32x4){0.f, 0.f, 0.f, 0.f};

  const int nt = K >> 6;   // BK = 64
  for (int kt = 0; kt < nt; kt++) {
    const int k0 = kt * 64;
    GLOAD16(Ab0 + k0, &As[ia0 * 8]);
    GLOAD16(Ab1 + k0, &As[ia1 * 8]);
    GLOAD16(Bb0 + k0, &Bs[ib0 * 8]);
    GLOAD16(Bb1 + k0, &Bs[ib1 * 8]);
    GLOAD16(Bb2 + k0, &Bs[ib2 * 8]);
    GLOAD16(Bb3 + k0, &Bs[ib3 * 8]);
    __syncthreads();                       // compiler drains vmcnt; hidden by co-block
    {
      short8 a[4], b[4];
      #pragma unroll
      for (int fm = 0; fm < 4; fm++) a[fm] = *(const short8*)((const char*)As + aoff[fm]);
      #pragma unroll
      for (int fn = 0; fn < 4; fn++) b[fn] = *(const short8*)((const char*)Bs + boff[fn]);
      #pragma unroll
      for (int fm = 0; fm < 4; fm++)
        #pragma unroll
        for (int fn = 0; fn < 4; fn++)
          acc[fm][fn] = MFMA16(a[fm], b[fn], acc[fm][fn]);
    }
    {
      short8 a[4], b[4];
      #pragma unroll
      for (int fm = 0; fm < 4; fm++) a[fm] = *(const short8*)((const char*)As + (aoff[fm] ^ 64));
      #pragma unroll
      for (int fn = 0; fn < 4; fn++) b[fn] = *(const short8*)((const char*)Bs + (boff[fn] ^ 64));
      #pragma unroll
      for (int fm = 0; fm < 4; fm++)
        #pragma unroll
        for (int fn = 0; fn < 4; fn++)
          acc[fm][fn] = MFMA16(a[fm], b[fn], acc[fm][fn]);
    }
    __syncthreads();
  }

  // ---------------- epilogue (round-10/12 proven) ----------------
  if (MODE == 2 || MODE == 3) {
    #pragma unroll
    for (int fn = 0; fn < 4; fn++) {
      const size_t gcol = tn + wn * 64 + fn * 16 + rm;
      const float bc = bias[gcol];
      #pragma unroll
      for (int fm = 0; fm < 4; fm++) {
        #pragma unroll
        for (int r = 0; r < 4; r++) {
          const size_t grow = tm + wm * 64 + fm * 16 + g * 4 + r;
          const size_t off = grow * (size_t)N + gcol;
          float v = acc[fm][fn][r] + bc;
          if (MODE == 2) ((float*)outp)[off] = v + res[off];
          else { float* op = (float*)outp; op[off] = v + op[off]; }
        }
      }
    }
  } else if (MODE == 0) {
    for (int half = 0; half < 2; half++) {
      __syncthreads();
      if ((w >> 2) == half) {
        unsigned short* eb = Sh + (w & 3) * 4096;
        if (z == 2) {
          // V^T slab [64 ch][64 tok]
          #pragma unroll
          for (int fn = 0; fn < 4; fn++) {
            const float bc = bias[tn + wn * 64 + fn * 16 + rm];
            #pragma unroll
            for (int fm = 0; fm < 4; fm++)
              #pragma unroll
              for (int r = 0; r < 4; r++) {
                const int tok = fm * 16 + g * 4 + r;
                const int ch  = fn * 16 + rm;
                eb[ch * 64 + (tok ^ ((ch & 7) << 3))] = f2bf(acc[fm][fn][r] + bc);
              }
          }
          const int tok0 = (int)tm + wm * 64;
          const int bb = tok0 >> 9, l0 = tok0 & 511;
          #pragma unroll
          for (int pass = 0; pass < 8; pass++) {
            const int ch = pass * 8 + (lane >> 3);
            const int t8 = (lane & 7) * 8;
            short8 vv = *(const short8*)&eb[ch * 64 + (t8 ^ ((ch & 7) << 3))];
            *(short8*)((unsigned short*)outp +
                       ((size_t)bb * 1024 + tn + wn * 64 + ch) * 512 + l0 + t8) = vv;
          }
        } else {
          // row-major slab [64 rows][64 cols]
          #pragma unroll
          for (int fn = 0; fn < 4; fn++) {
            const float bc = bias[tn + wn * 64 + fn * 16 + rm];
            #pragma unroll
            for (int fm = 0; fm < 4; fm++)
              #pragma unroll
              for (int r = 0; r < 4; r++) {
                float v = acc[fm][fn][r] + bc;
                if (z == 0) v *= 0.125f;
                const int lr = fm * 16 + g * 4 + r;
                const int lc = fn * 16 + rm;
                eb[lr * 64 + (lc ^ (g << 4))] = f2bf(v);
              }
          }
          #pragma unroll
          for (int pass = 0; pass < 8; pass++) {
            const int lr = pass * 8 + (lane >> 3);
            const int lc8 = (lane & 7) * 8;
            const int q = (lr >> 2) & 3;
            short8 vv = *(const short8*)&eb[lr * 64 + (lc8 ^ (q << 4))];
            *(short8*)((unsigned short*)outp +
                       (tm + wm * 64 + lr) * (size_t)N + tn + wn * 64 + lc8) = vv;
          }
        }
      }
    }
  } else {
    for (int half = 0; half < 2; half++) {
      __syncthreads();
      if ((w >> 2) == half) {
        unsigned short* eb = Sh + (w & 3) * 4096;
        #pragma unroll
        for (int fn = 0; fn < 4; fn++) {
          const float bc = bias[tn + wn * 64 + fn * 16 + rm];
          #pragma unroll
          for (int fm = 0; fm < 4; fm++)
            #pragma unroll
            for (int r = 0; r < 4; r++) {
              const int lr = fm * 16 + g * 4 + r;
              const int lc = fn * 16 + rm;
              eb[lr * 64 + (lc ^ (g << 4))] = f2bf(gelu_f(acc[fm][fn][r] + bc));
            }
        }
        #pragma unroll
        for (int pass = 0; pass < 8; pass++) {
          const int lr = pass * 8 + (lane >> 3);
          const int lc8 = (lane & 7) * 8;
          const int q = (lr >> 2) & 3;
          short8 vv = *(const short8*)&eb[lr * 64 + (lc8 ^ (q << 4))];
          *(short8*)((unsigned short*)outp +
                     (tm + wm * 64 + lr) * (size_t)N + tn + wn * 64 + lc8) = vv;
        }
      }
    }
  }
}

// ---------------- MFMA flash attention: KVBLK=64, Q-region reuse, single-buffer --
// LDS 34 KB (Q 16 KB reused as K 8 + V 8 after frag read; Ps 18 KB) -> 4 blocks/CU.
// Half the kv-iterations (8) -> half the shfl-max rounds + barriers of KVBLK=32.
// Single-buffered K/V: stage -> barrier -> compute -> barrier; co-resident blocks
// hide the stage latency (m114; round-13 showed explicit dbuf is neutral/worse).
// defer-max (T13, THR=8) + deferred l-reduce carried over (round-10 verified).
__global__ __launch_bounds__(256) void attn_mfma(
    const unsigned short* __restrict__ qb, const unsigned short* __restrict__ kb,
    const unsigned short* __restrict__ vt, unsigned short* __restrict__ ctx)
{
  __shared__ unsigned short Sh[8192];          // 16 KB: Q(128x64hw) -> K(64x64)|V(64x64)
  __shared__ unsigned short Ps[4][32 * 72];    // 18 KB (144B rows: rm/rm+8 2-way = free)
  unsigned short* Ks = Sh;                     // rows kv 0..63, 128 B/row, swz (r&7)
  unsigned short* Vs = Sh + 4096;              // rows d 0..63, 128 B/row, swz (r&7)
  const int t = threadIdx.x;
  const int lane = t & 63, w = t >> 6;
  const int g = lane >> 4, rm = lane & 15;
  const int qt = blockIdx.x, h = blockIdx.y, b = blockIdx.z;

  const unsigned short* qg = qb + ((size_t)(b * SEQ + qt * 128)) * DMOD + h * DHEAD;
  const unsigned short* kg = kb + ((size_t)(b * SEQ)) * DMOD + h * DHEAD;
  const unsigned short* vg = vt + ((size_t)(b * NHEAD + h)) * DHEAD * SEQ;  // [64][512]

  // ---- stage Q into Sh (row-swizzled, proven round-3 pattern) ----
  #pragma unroll
  for (int ii = 0; ii < 4; ii++) {
    const int i = ii * 256 + t;
    const int r = i >> 3, c = i & 7;
    const int bc = 16 * (c ^ (r & 7));
    GLOAD16(qg + (size_t)r * DMOD + (bc >> 1), Sh + (size_t)(ii * 256 + w * 64) * 8);
  }
  __syncthreads();

  short8 aq[2][2];
  #pragma unroll
  for (int fq = 0; fq < 2; fq++)
    #pragma unroll
    for (int kd = 0; kd < 2; kd++) {
      const int r = w * 32 + fq * 16 + rm;
      aq[fq][kd] = *(const short8*)((const char*)Sh + r * 128 + ((kd * 64 + g * 16) ^ ((r & 7) << 4)));
    }
  __syncthreads();   // all aq reads done before K/V staging overwrites Q region

  float mrow[2][4], lsum[2][4];
  f32x4 of[2][4];
  #pragma unroll
  for (int fq = 0; fq < 2; fq++) {
    #pragma unroll
    for (int j = 0; j < 4; j++) { mrow[fq][j] = -INFINITY; lsum[fq][j] = 0.f; }
    #pragma unroll
    for (int fd = 0; fd < 4; fd++) of[fq][fd] = (f32x4){0.f, 0.f, 0.f, 0.f};
  }

  for (int kt = 0; kt < SEQ / 64; kt++) {
    // ---- stage K (64 kv x 128B) + V^T (64 d x 128B), 2 chunks/thread each ----
    {
      const int i = t, r = i >> 3, c = i & 7;
      const int bc = 16 * (c ^ (r & 7));
      GLOAD16(kg + (size_t)(kt * 64 + r) * DMOD + (bc >> 1), Ks + (size_t)w * 512);
    }
    {
      const int i = 256 + t, r = i >> 3, c = i & 7;
      const int bc = 16 * (c ^ (r & 7));
      GLOAD16(kg + (size_t)(kt * 64 + r) * DMOD + (bc >> 1), Ks + 2048 + (size_t)w * 512);
    }
    {
      const int i = t, r = i >> 3, c = i & 7;
      const int bc = 16 * (c ^ (r & 7));
      GLOAD16(vg + (size_t)r * SEQ + kt * 64 + (bc >> 1), Vs + (size_t)w * 512);
    }
    {
      const int i = 256 + t, r = i >> 3, c = i & 7;
      const int bc = 16 * (c ^ (r & 7));
      GLOAD16(vg + (size_t)r * SEQ + kt * 64 + (bc >> 1), Vs + 2048 + (size_t)w * 512);
    }
    __syncthreads();

    // ---- S = Q K^T (per wave: 32q x 64k) ----
    f32x4 s[2][4];
    #pragma unroll
    for (int fq = 0; fq < 2; fq++)
      #pragma unroll
      for (int fk = 0; fk < 4; fk++) {
        f32x4 a = (f32x4){0.f, 0.f, 0.f, 0.f};
        #pragma unroll
        for (int kd = 0; kd < 2; kd++) {
          const int r = fk * 16 + rm;
          short8 bk = *(const short8*)((const char*)Ks + r * 128 + ((kd * 64 + g * 16) ^ ((r & 7) << 4)));
          a = MFMA16(aq[fq][kd], bk, a);
        }
        s[fq][fk] = a;
      }

    // ---- online softmax: tile row-max + defer-max gate ----
    float pm[2][4];
    int grow = 0;
    #pragma unroll
    for (int fq = 0; fq < 2; fq++)
      #pragma unroll
      for (int j = 0; j < 4; j++) {
        float mx = fmaxf(fmaxf(s[fq][0][j], s[fq][1][j]), fmaxf(s[fq][2][j], s[fq][3][j]));
        #pragma unroll
        for (int mk = 1; mk < 16; mk <<= 1) mx = fmaxf(mx, __shfl_xor(mx, mk));
        pm[fq][j] = mx;
        grow |= (mx > mrow[fq][j] + 8.f);
      }
    if (__any(grow)) {
      #pragma unroll
      for (int fq = 0; fq < 2; fq++)
        #pragma unroll
        for (int j = 0; j < 4; j++) {
          const float mn = fmaxf(mrow[fq][j], pm[fq][j]);
          const float corr = __expf(mrow[fq][j] - mn);
          mrow[fq][j] = mn;
          lsum[fq][j] *= corr;
          #pragma unroll
          for (int fd = 0; fd < 4; fd++) of[fq][fd][j] *= corr;
        }
    }
    #pragma unroll
    for (int fq = 0; fq < 2; fq++)
      #pragma unroll
      for (int j = 0; j < 4; j++) {
        const int prow = (fq * 16 + g * 4 + j) * 72;
        float psum = 0.f;
        #pragma unroll
        for (int fk = 0; fk < 4; fk++) {
          const float p = __expf(s[fq][fk][j] - mrow[fq][j]);
          psum += p;
          Ps[w][prow + fk * 16 + rm] = f2bf(p);
        }
        lsum[fq][j] += psum;
      }

    // ---- O += P V (ks = two 32-wide l-slots) ----
    #pragma unroll
    for (int fq = 0; fq < 2; fq++) {
      short8 pa0 = *(const short8*)&Ps[w][(fq * 16 + rm) * 72 + g * 8];
      short8 pa1 = *(const short8*)&Ps[w][(fq * 16 + rm) * 72 + 32 + g * 8];
      #pragma unroll
      for (int fd = 0; fd < 4; fd++) {
        const int r = fd * 16 + rm;
        const short8 vb0 = *(const short8*)((const char*)Vs + r * 128 + ((g * 16) ^ ((r & 7) << 4)));
        const short8 vb1 = *(const short8*)((const char*)Vs + r * 128 + ((64 + g * 16) ^ ((r & 7) << 4)));
        of[fq][fd] = MFMA16(pa0, vb0, of[fq][fd]);
        of[fq][fd] = MFMA16(pa1, vb1, of[fq][fd]);
      }
    }

    __syncthreads();
  }

  // deferred 16-lane l reduction, then normalize + store
  #pragma unroll
  for (int fq = 0; fq < 2; fq++)
    #pragma unroll
    for (int j = 0; j < 4; j++) {
      float ls = lsum[fq][j];
      #pragma unroll
      for (int mk = 1; mk < 16; mk <<= 1) ls += __shfl_xor(ls, mk);
      const float inv = 1.f / ls;
      const size_t q = (size_t)b * SEQ + qt * 128 + w * 32 + fq * 16 + g * 4 + j;
      #pragma unroll
      for (int fd = 0; fd < 4; fd++)
        ctx[q * DMOD + h * DHEAD + fd * 16 + rm] = f2bf(of[fq][fd][j] * inv);
    }
}

extern "C" void kernel_launch(void* const* d_in, const int* in_sizes, int n_in,
                              void* d_out, int out_size, void* d_ws, size_t ws_size,
                              hipStream_t stream) {
  const float* x_a   = (const float*)d_in[0];
  const float* x_b   = (const float*)d_in[1];
  const float* spk   = (const float*)d_in[2];
  const float* Wq    = (const float*)d_in[3];
  const float* bq    = (const float*)d_in[4];
  const float* Wk    = (const float*)d_in[5];
  const float* bk    = (const float*)d_in[6];
  const float* Wv    = (const float*)d_in[7];
  const float* bv    = (const float*)d_in[8];
  const float* Wo    = (const float*)d_in[9];
  const float* bo    = (const float*)d_in[10];
  const float* ln_g  = (const float*)d_in[11];
  const float* ln_b  = (const float*)d_in[12];
  const float* fln_g = (const float*)d_in[13];
  const float* fln_b = (const float*)d_in[14];
  const float* W1    = (const float*)d_in[15];
  const float* b1    = (const float*)d_in[16];
  const float* W2    = (const float*)d_in[17];
  const float* b2    = (const float*)d_in[18];
  float* out = (float*)d_out;           // also serves as the f32 x_b master (X)

  char* ws = (char*)d_ws;
  size_t o = 0;
  auto give = [&](size_t bytes) { char* p = ws + o; o += (bytes + 255) & ~(size_t)255; return p; };
  const size_t ACT2 = (size_t)NTOK * DMOD * 2;   // 32 MB bf16 activation

  unsigned short* qb16  = (unsigned short*)give(ACT2);
  unsigned short* kb16  = (unsigned short*)give(ACT2);
  unsigned short* vt16  = (unsigned short*)give(ACT2);       // V^T [b][h][d][l]
  unsigned short* ctx16 = (unsigned short*)give(ACT2);
  unsigned short* xa16  = (unsigned short*)give(ACT2);
  unsigned short* xbn16 = (unsigned short*)give(ACT2);
  float*          outf  = (float*)give((size_t)NTOK * DMOD * 4);   // 64 MB (residual stream)
  unsigned short* Wqt   = (unsigned short*)give((size_t)DMOD * DMOD * 2);
  unsigned short* Wkt   = (unsigned short*)give((size_t)DMOD * DMOD * 2);
  unsigned short* Wvt   = (unsigned short*)give((size_t)DMOD * DMOD * 2);
  unsigned short* Wot   = (unsigned short*)give((size_t)DMOD * DMOD * 2);
  unsigned short* W1t   = (unsigned short*)give((size_t)DMOD * DFFN * 2);
  unsigned short* W2t   = (unsigned short*)give((size_t)DMOD * DFFN * 2);
  float*          peb   = (float*)give((size_t)SEQ * DMOD * 4);
  unsigned short* inter = qb16;     // 128 MB span over qb16..ctx16 (dead during FFN)
  (void)ws_size; (void)in_sizes; (void)n_in; (void)out_size;

  const dim3 blk(256);
  const dim3 blk512(512);

  pe_kernel<<<dim3((SEQ * (DMOD / 2)) / 256), blk, 0, stream>>>(peb);
  const int nprep = (NTOK * DMOD / 4) / 256;
  prep_kernel<<<dim3(nprep), blk, 0, stream>>>(x_a, peb, spk, nullptr, xa16);
  prep_kernel<<<dim3(nprep), blk, 0, stream>>>(x_b, peb, spk, out, xbn16);

  const dim3 gQKV(DMOD / 256, NTOK / 128, 3);   // (4,128,3) = 1536 blocks
  const dim3 gWO (DMOD / 256, NTOK / 128);      // (4,128)   = 512
  const dim3 gW1 (DFFN / 256, NTOK / 128);      // (16,128)  = 2048
  const dim3 gW2 (DMOD / 256, NTOK / 128);      // (4,128)   = 512

  for (int i = 0; i < NLAY; i++) {
    wtrans_all<<<dim3(3072), blk, 0, stream>>>(Wq, Wk, Wv, Wo, W1, W2, i,
                                               Wqt, Wkt, Wvt, Wot, W1t, W2t);
    if (i != 0) {
      ln_kernel<1><<<dim3(NTOK), blk, 0, stream>>>(out, ln_g + (size_t)i * DMOD, ln_b + (size_t)i * DMOD, outf, xbn16);
    }
    gemm128<0><<<gQKV, blk512, 0, stream>>>(
        xbn16, xa16, Wqt, Wkt, Wvt,
        bq + (size_t)i * DMOD, bk + (size_t)i * DMOD, bv + (size_t)i * DMOD,
        nullptr, qb16, kb16, vt16, DMOD, DMOD);
    attn_mfma<<<dim3(SEQ / 128, NHEAD, BATCH), blk, 0, stream>>>(qb16, kb16, vt16, ctx16);
    if (i == 0) {
      gemm128<2><<<gWO, blk512, 0, stream>>>(
          ctx16, nullptr, Wot, nullptr, nullptr,
          bo + (size_t)i * DMOD, nullptr, nullptr, out, outf, nullptr, nullptr, DMOD, DMOD);
    } else {
      gemm128<3><<<gWO, blk512, 0, stream>>>(
          ctx16, nullptr, Wot, nullptr, nullptr,
          bo + (size_t)i * DMOD, nullptr, nullptr, nullptr, outf, nullptr, nullptr, DMOD, DMOD);
    }
    ln_kernel<0><<<dim3(NTOK), blk, 0, stream>>>(outf, fln_g + (size_t)i * DMOD, fln_b + (size_t)i * DMOD, nullptr, xbn16);
    gemm128<1><<<gW1, blk512, 0, stream>>>(
        xbn16, nullptr, W1t, nullptr, nullptr,
        b1 + (size_t)i * DFFN, nullptr, nullptr, nullptr, inter, nullptr, nullptr, DFFN, DMOD);
    gemm128<2><<<gW2, blk512, 0, stream>>>(
        inter, nullptr, W2t, nullptr, nullptr,
        b2 + (size_t)i * DMOD, nullptr, nullptr, outf, out, nullptr, nullptr, DMOD, DFFN);
  }
}

// Round 15
// 2627.566 us; speedup vs baseline: 1.1201x; 1.0325x over previous
//
#include <hip/hip_runtime.h>

// Problem dims (fixed)
#define BATCH 32
#define SEQ   512
#define DMOD  1024
#define DFFN  4096
#define NHEAD 16
#define DHEAD 64
#define NLAY  4
#define NTOK  (BATCH * SEQ)   // 16384

typedef __attribute__((ext_vector_type(8))) short short8;
typedef __attribute__((ext_vector_type(4))) float f32x4;
typedef unsigned int uint32;

__device__ __forceinline__ unsigned short f2bf(float f) {
  uint32 u = __builtin_bit_cast(uint32, f);
  u += 0x7fffu + ((u >> 16) & 1u);             // RNE
  return (unsigned short)(u >> 16);
}
__device__ __forceinline__ float gelu_f(float x) {
  float u = 0.7978845608028654f * (x + 0.044715f * x * x * x);
  u = fminf(fmaxf(u, -15.f), 15.f);
  float e = __expf(2.f * u);
  return 0.5f * x * (1.f + (e - 1.f) / (e + 1.f));
}

#define GLOAD16(g, l) __builtin_amdgcn_global_load_lds( \
    (const __attribute__((address_space(1))) void*)(g), \
    (__attribute__((address_space(3))) void*)(l), 16, 0, 0)

#define MFMA16(a, b, c) __builtin_amdgcn_mfma_f32_16x16x32_bf16((a), (b), (c), 0, 0, 0)

// ---------------- positional encoding table: pe[l][d], 512x1024 ----------------
__global__ __launch_bounds__(256) void pe_kernel(float* __restrict__ pe) {
  const int idx = blockIdx.x * 256 + threadIdx.x;   // 0 .. 512*512-1 (pairs)
  const int l = idx >> 9;
  const int i = idx & 511;
  const float dv = __expf((float)(2 * i) * (-9.210340371976184f / (float)DMOD));
  const float a = (float)l * dv;
  pe[(size_t)l * DMOD + 2 * i]     = sinf(a);
  pe[(size_t)l * DMOD + 2 * i + 1] = cosf(a);
}

// ---------------- x + pe + speaker -> (optional f32) + bf16 (fused a/b via z) ----
__global__ __launch_bounds__(256) void prep_kernel(
    const float* __restrict__ xa, const float* __restrict__ xb,
    const float* __restrict__ pe, const float* __restrict__ spk,
    float* __restrict__ xb32, unsigned short* __restrict__ oa16,
    unsigned short* __restrict__ ob16)
{
  const int z = blockIdx.z;
  const float* x = z ? xb : xa;
  unsigned short* o16 = z ? ob16 : oa16;
  const size_t id4 = (size_t)blockIdx.x * 256 + threadIdx.x;  // over B*L*D/4
  const size_t e = id4 * 4;
  const int b  = (int)(e >> 19);
  const int ld = (int)(e & ((1u << 19) - 1));
  const int d  = (int)(e & 1023);
  float4 xv = ((const float4*)x)[id4];
  float4 pv = ((const float4*)pe)[ld >> 2];
  float4 sv = ((const float4*)spk)[(size_t)b * 256 + (d >> 2)];
  float4 o;
  o.x = xv.x + pv.x + sv.x;
  o.y = xv.y + pv.y + sv.y;
  o.z = xv.z + pv.z + sv.z;
  o.w = xv.w + pv.w + sv.w;
  if (z) ((float4*)xb32)[id4] = o;
  ushort4 h;
  h.x = f2bf(o.x); h.y = f2bf(o.y); h.z = f2bf(o.z); h.w = f2bf(o.w);
  ((ushort4*)o16)[id4] = h;
}

// ---------------- merged per-layer weight transpose: all 6 weights ----------------
__global__ __launch_bounds__(256) void wtrans_all(
    const float* __restrict__ Wq, const float* __restrict__ Wk,
    const float* __restrict__ Wv, const float* __restrict__ Wo,
    const float* __restrict__ W1, const float* __restrict__ W2, int layer,
    unsigned short* __restrict__ Wqt, unsigned short* __restrict__ Wkt,
    unsigned short* __restrict__ Wvt, unsigned short* __restrict__ Wot,
    unsigned short* __restrict__ W1t, unsigned short* __restrict__ W2t)
{
  __shared__ float tile[64][65];
  const int bid = blockIdx.x;
  const float* W; unsigned short* Wt; int K, N, bx, by;
  if (bid < 1024) {
    const int which = bid >> 8, r = bid & 255;
    bx = r & 15; by = r >> 4; K = DMOD; N = DMOD;
    const size_t off = (size_t)layer * DMOD * DMOD;
    W  = (which == 0 ? Wq : which == 1 ? Wk : which == 2 ? Wv : Wo) + off;
    Wt = (which == 0 ? Wqt : which == 1 ? Wkt : which == 2 ? Wvt : Wot);
  } else if (bid < 2048) {
    const int r = bid - 1024;
    bx = r & 63; by = r >> 6; K = DMOD; N = DFFN;
    W = W1 + (size_t)layer * DMOD * DFFN; Wt = W1t;
  } else {
    const int r = bid - 2048;
    bx = r & 15; by = r >> 4; K = DFFN; N = DMOD;
    W = W2 + (size_t)layer * DMOD * DFFN; Wt = W2t;
  }
  const int n0 = bx * 64, k0 = by * 64;
  const int tx = threadIdx.x & 63, ty = threadIdx.x >> 6;
  #pragma unroll
  for (int i = 0; i < 16; i++) {
    int r = ty + 4 * i;
    tile[r][tx] = W[(size_t)(k0 + r) * N + n0 + tx];
  }
  __syncthreads();
  #pragma unroll
  for (int i = 0; i < 16; i++) {
    int rn = ty + 4 * i;
    Wt[(size_t)(n0 + rn) * K + k0 + tx] = f2bf(tile[tx][rn]);
  }
}

// ---------------- LayerNorm: one block per row (1024 cols) ----------------
template<int WRITE_F32>
__global__ __launch_bounds__(256) void ln_kernel(
    const float* __restrict__ x, const float* __restrict__ g, const float* __restrict__ bta,
    float* __restrict__ of32, unsigned short* __restrict__ o16)
{
  const int row = blockIdx.x;
  const int t = threadIdx.x;
  const float4 v = ((const float4*)(x + (size_t)row * DMOD))[t];
  float s  = v.x + v.y + v.z + v.w;
  float s2 = v.x*v.x + v.y*v.y + v.z*v.z + v.w*v.w;
  #pragma unroll
  for (int off = 32; off > 0; off >>= 1) {
    s  += __shfl_down(s, off);
    s2 += __shfl_down(s2, off);
  }
  __shared__ float red[8];
  if ((t & 63) == 0) { red[(t >> 6) * 2] = s; red[(t >> 6) * 2 + 1] = s2; }
  __syncthreads();
  const float sum  = red[0] + red[2] + red[4] + red[6];
  const float sum2 = red[1] + red[3] + red[5] + red[7];
  const float mean = sum * (1.f / (float)DMOD);
  const float var  = sum2 * (1.f / (float)DMOD) - mean * mean;
  const float rstd = rsqrtf(var + 1e-6f);
  const float4 gg = ((const float4*)g)[t];
  const float4 bb = ((const float4*)bta)[t];
  float4 o;
  o.x = (v.x - mean) * rstd * gg.x + bb.x;
  o.y = (v.y - mean) * rstd * gg.y + bb.y;
  o.z = (v.z - mean) * rstd * gg.z + bb.z;
  o.w = (v.w - mean) * rstd * gg.w + bb.w;
  if (WRITE_F32) ((float4*)of32)[(size_t)row * 256 + t] = o;
  ushort4 h;
  h.x = f2bf(o.x); h.y = f2bf(o.y); h.z = f2bf(o.z); h.w = f2bf(o.w);
  ((ushort4*)o16)[(size_t)row * 256 + t] = h;
}

// ---------------- GEMM 128x256, 8 waves, BK=64 single-buffer (ROUND-12/14 BEST) --
// 64 KB LDS (stage uses 48 KB; epilogue uses all 64 KB as 8 private wave slabs ->
// ZERO epilogue barriers, no half-pass serialization). Occupancy unchanged:
// measured 41-42% = 2 blocks/CU, and 160/64 = 2. Swizzle for 128B rows:
// 16B-chunk idx (3b) ^ (row&7), both sides; 2 lanes/bank-slot = free.
// launch_bounds(512,4): round-9 lesson — never raise min-waves blind.
// MODE 0: fused QKV via grid.z: z=0 Q (bias,*0.125,bf16), z=1 K (bias,bf16),
//         z=2 V (bias, bf16 V^T [b][ch][l]).  A = z?A1:A0.
// MODE 1: bias+gelu->bf16 (W1).  MODE 2: bias+res->f32.  MODE 3: bias+inplace->f32.
template<int MODE>
__global__ __launch_bounds__(512, 4) void gemm128(
    const unsigned short* __restrict__ A0, const unsigned short* __restrict__ A1,
    const unsigned short* __restrict__ B0, const unsigned short* __restrict__ B1,
    const unsigned short* __restrict__ B2,
    const float* __restrict__ bias0, const float* __restrict__ bias1,
    const float* __restrict__ bias2, const float* __restrict__ res,
    void* out0, void* out1, void* out2, int N, int K)
{
  __shared__ unsigned short Sh[32768];   // 64 KB: stage As[0,8192) Bs[8192,24576)
  unsigned short* As = Sh;               // 128 rows x 64 hw (128 B/row)
  unsigned short* Bs = Sh + 8192;        // 256 rows x 64 hw
  const int t = threadIdx.x;
  const int lane = t & 63, w = t >> 6;
  const int wm = w >> 2, wn = w & 3;     // 2(M) x 4(N) wave grid; wave owns 64x64
  const int g = lane >> 4, rm = lane & 15;

  // XCD-aware bijective remap over the whole (possibly 3D) grid
  const int gx = gridDim.x, gy = gridDim.y;
  const int nwg = gx * gy * gridDim.z;
  const int hid = (blockIdx.z * gy + blockIdx.y) * gx + blockIdx.x;
  const int wid = (hid & 7) * (nwg >> 3) + (hid >> 3);
  const int bx = wid % gx;
  const int rest = wid / gx;
  const int by = rest % gy;
  const int z  = rest / gy;              // 0 for 2D grids

  const unsigned short* A  = (MODE == 0 && z) ? A1 : A0;
  const unsigned short* Bt = (MODE == 0) ? (z == 0 ? B0 : z == 1 ? B1 : B2) : B0;
  const float* bias        = (MODE == 0) ? (z == 0 ? bias0 : z == 1 ? bias1 : bias2) : bias0;
  void* outp               = (MODE == 0) ? (z == 0 ? out0 : z == 1 ? out1 : out2) : out0;

  const size_t tm = (size_t)by * 128;
  const size_t tn = (size_t)bx * 256;

  // staging per K-tile: A 1024 16B-chunks (2/thread), B 2048 (4/thread).
  // chunk row = idx>>3; chunk-in-row (3b) pre-swizzled: ^ (row&7). Dest linear.
  const int ia0 = t, ia1 = 512 + t;
  const int ra0 = ia0 >> 3, ra1 = ia1 >> 3;
  const int ca0 = 8 * ((ia0 & 7) ^ (ra0 & 7));
  const int ca1 = 8 * ((ia1 & 7) ^ (ra1 & 7));
  const int ib0 = t, ib1 = 512 + t, ib2 = 1024 + t, ib3 = 1536 + t;
  const int rb0 = ib0 >> 3, rb1 = ib1 >> 3, rb2 = ib2 >> 3, rb3 = ib3 >> 3;
  const int cb0 = 8 * ((ib0 & 7) ^ (rb0 & 7));
  const int cb1 = 8 * ((ib1 & 7) ^ (rb1 & 7));
  const int cb2 = 8 * ((ib2 & 7) ^ (rb2 & 7));
  const int cb3 = 8 * ((ib3 & 7) ^ (rb3 & 7));
  const unsigned short* Ab0 = A + (tm + ra0) * (size_t)K + ca0;
  const unsigned short* Ab1 = A + (tm + ra1) * (size_t)K + ca1;
  const unsigned short* Bb0 = Bt + (tn + rb0) * (size_t)K + cb0;
  const unsigned short* Bb1 = Bt + (tn + rb1) * (size_t)K + cb1;
  const unsigned short* Bb2 = Bt + (tn + rb2) * (size_t)K + cb2;
  const unsigned short* Bb3 = Bt + (tn + rb3) * (size_t)K + cb3;

  // swizzled fragment read offsets (bytes), kd=0; kd=1 is ^64
  int aoff[4], boff[4];
  #pragma unroll
  for (int fm = 0; fm < 4; fm++) {
    const int r = wm * 64 + fm * 16 + rm;
    aoff[fm] = r * 128 + ((g ^ (r & 7)) * 16);
  }
  #pragma unroll
  for (int fn = 0; fn < 4; fn++) {
    const int r = wn * 64 + fn * 16 + rm;
    boff[fn] = r * 128 + ((g ^ (r & 7)) * 16);
  }

  f32x4 acc[4][4];
  #pragma unroll
  for (int i = 0; i < 4; i++)
    #pragma unroll
    for (int j = 0; j < 4; j++)
      acc[i][j] = (f32x4){0.f, 0.f, 0.f, 0.f};

  const int nt = K >> 6;   // BK = 64
  for (int kt = 0; kt < nt; kt++) {
    const int k0 = kt * 64;
    GLOAD16(Ab0 + k0, &As[ia0 * 8]);
    GLOAD16(Ab1 + k0, &As[ia1 * 8]);
    GLOAD16(Bb0 + k0, &Bs[ib0 * 8]);
    GLOAD16(Bb1 + k0, &Bs[ib1 * 8]);
    GLOAD16(Bb2 + k0, &Bs[ib2 * 8]);
    GLOAD16(Bb3 + k0, &Bs[ib3 * 8]);
    __syncthreads();                       // compiler drains vmcnt; hidden by co-block
    {
      short8 a[4], b[4];
      #pragma unroll
      for (int fm = 0; fm < 4; fm++) a[fm] = *(const short8*)((const char*)As + aoff[fm]);
      #pragma unroll
      for (int fn = 0; fn < 4; fn++) b[fn] = *(const short8*)((const char*)Bs + boff[fn]);
      #pragma unroll
      for (int fm = 0; fm < 4; fm++)
        #pragma unroll
        for (int fn = 0; fn < 4; fn++)
          acc[fm][fn] = MFMA16(a[fm], b[fn], acc[fm][fn]);
    }
    {
      short8 a[4], b[4];
      #pragma unroll
      for (int fm = 0; fm < 4; fm++) a[fm] = *(const short8*)((const char*)As + (aoff[fm] ^ 64));
      #pragma unroll
      for (int fn = 0; fn < 4; fn++) b[fn] = *(const short8*)((const char*)Bs + (boff[fn] ^ 64));
      #pragma unroll
      for (int fm = 0; fm < 4; fm++)
        #pragma unroll
        for (int fn = 0; fn < 4; fn++)
          acc[fm][fn] = MFMA16(a[fm], b[fn], acc[fm][fn]);
    }
    __syncthreads();
  }
  // After the final barrier all LDS reads are complete; each wave now uses its
  // OWN 8 KB slab (Sh + w*4096 hw) for the bf16 bounce -> no barriers needed.

  if (MODE == 2 || MODE == 3) {
    #pragma unroll
    for (int fn = 0; fn < 4; fn++) {
      const size_t gcol = tn + wn * 64 + fn * 16 + rm;
      const float bc = bias[gcol];
      #pragma unroll
      for (int fm = 0; fm < 4; fm++) {
        #pragma unroll
        for (int r = 0; r < 4; r++) {
          const size_t grow = tm + wm * 64 + fm * 16 + g * 4 + r;
          const size_t off = grow * (size_t)N + gcol;
          float v = acc[fm][fn][r] + bc;
          if (MODE == 2) ((float*)outp)[off] = v + res[off];
          else { float* op = (float*)outp; op[off] = v + op[off]; }
        }
      }
    }
  } else if (MODE == 0) {
    unsigned short* eb = Sh + w * 4096;    // private slab, no cross-wave sharing
    if (z == 2) {
      // V^T slab [64 ch][64 tok]
      #pragma unroll
      for (int fn = 0; fn < 4; fn++) {
        const float bc = bias[tn + wn * 64 + fn * 16 + rm];
        #pragma unroll
        for (int fm = 0; fm < 4; fm++)
          #pragma unroll
          for (int r = 0; r < 4; r++) {
            const int tok = fm * 16 + g * 4 + r;
            const int ch  = fn * 16 + rm;
            eb[ch * 64 + (tok ^ ((ch & 7) << 3))] = f2bf(acc[fm][fn][r] + bc);
          }
      }
      const int tok0 = (int)tm + wm * 64;
      const int bb = tok0 >> 9, l0 = tok0 & 511;
      #pragma unroll
      for (int pass = 0; pass < 8; pass++) {
        const int ch = pass * 8 + (lane >> 3);
        const int t8 = (lane & 7) * 8;
        short8 vv = *(const short8*)&eb[ch * 64 + (t8 ^ ((ch & 7) << 3))];
        *(short8*)((unsigned short*)outp +
                   ((size_t)bb * 1024 + tn + wn * 64 + ch) * 512 + l0 + t8) = vv;
      }
    } else {
      // row-major slab [64 rows][64 cols]
      #pragma unroll
      for (int fn = 0; fn < 4; fn++) {
        const float bc = bias[tn + wn * 64 + fn * 16 + rm];
        #pragma unroll
        for (int fm = 0; fm < 4; fm++)
          #pragma unroll
          for (int r = 0; r < 4; r++) {
            float v = acc[fm][fn][r] + bc;
            if (z == 0) v *= 0.125f;
            const int lr = fm * 16 + g * 4 + r;
            const int lc = fn * 16 + rm;
            eb[lr * 64 + (lc ^ (g << 4))] = f2bf(v);
          }
      }
      #pragma unroll
      for (int pass = 0; pass < 8; pass++) {
        const int lr = pass * 8 + (lane >> 3);
        const int lc8 = (lane & 7) * 8;
        const int q = (lr >> 2) & 3;
        short8 vv = *(const short8*)&eb[lr * 64 + (lc8 ^ (q << 4))];
        *(short8*)((unsigned short*)outp +
                   (tm + wm * 64 + lr) * (size_t)N + tn + wn * 64 + lc8) = vv;
      }
    }
  } else {
    // MODE 1: gelu bf16 row-major, private slab
    unsigned short* eb = Sh + w * 4096;
    #pragma unroll
    for (int fn = 0; fn < 4; fn++) {
      const float bc = bias[tn + wn * 64 + fn * 16 + rm];
      #pragma unroll
      for (int fm = 0; fm < 4; fm++)
        #pragma unroll
        for (int r = 0; r < 4; r++) {
          const int lr = fm * 16 + g * 4 + r;
          const int lc = fn * 16 + rm;
          eb[lr * 64 + (lc ^ (g << 4))] = f2bf(gelu_f(acc[fm][fn][r] + bc));
        }
    }
    #pragma unroll
    for (int pass = 0; pass < 8; pass++) {
      const int lr = pass * 8 + (lane >> 3);
      const int lc8 = (lane & 7) * 8;
      const int q = (lr >> 2) & 3;
      short8 vv = *(const short8*)&eb[lr * 64 + (lc8 ^ (q << 4))];
      *(short8*)((unsigned short*)outp +
                 (tm + wm * 64 + lr) * (size_t)N + tn + wn * 64 + lc8) = vv;
    }
  }
}

// ---------------- MFMA flash attention: KVBLK=64, Q-region reuse (ROUND-14) -----
__global__ __launch_bounds__(256) void attn_mfma(
    const unsigned short* __restrict__ qb, const unsigned short* __restrict__ kb,
    const unsigned short* __restrict__ vt, unsigned short* __restrict__ ctx)
{
  __shared__ unsigned short Sh[8192];          // 16 KB: Q(128x64hw) -> K(64x64)|V(64x64)
  __shared__ unsigned short Ps[4][32 * 72];    // 18 KB (144B rows: rm/rm+8 2-way = free)
  unsigned short* Ks = Sh;                     // rows kv 0..63, 128 B/row, swz (r&7)
  unsigned short* Vs = Sh + 4096;              // rows d 0..63, 128 B/row, swz (r&7)
  const int t = threadIdx.x;
  const int lane = t & 63, w = t >> 6;
  const int g = lane >> 4, rm = lane & 15;
  const int qt = blockIdx.x, h = blockIdx.y, b = blockIdx.z;

  const unsigned short* qg = qb + ((size_t)(b * SEQ + qt * 128)) * DMOD + h * DHEAD;
  const unsigned short* kg = kb + ((size_t)(b * SEQ)) * DMOD + h * DHEAD;
  const unsigned short* vg = vt + ((size_t)(b * NHEAD + h)) * DHEAD * SEQ;  // [64][512]

  #pragma unroll
  for (int ii = 0; ii < 4; ii++) {
    const int i = ii * 256 + t;
    const int r = i >> 3, c = i & 7;
    const int bc = 16 * (c ^ (r & 7));
    GLOAD16(qg + (size_t)r * DMOD + (bc >> 1), Sh + (size_t)(ii * 256 + w * 64) * 8);
  }
  __syncthreads();

  short8 aq[2][2];
  #pragma unroll
  for (int fq = 0; fq < 2; fq++)
    #pragma unroll
    for (int kd = 0; kd < 2; kd++) {
      const int r = w * 32 + fq * 16 + rm;
      aq[fq][kd] = *(const short8*)((const char*)Sh + r * 128 + ((kd * 64 + g * 16) ^ ((r & 7) << 4)));
    }
  __syncthreads();   // all aq reads done before K/V staging overwrites Q region

  float mrow[2][4], lsum[2][4];
  f32x4 of[2][4];
  #pragma unroll
  for (int fq = 0; fq < 2; fq++) {
    #pragma unroll
    for (int j = 0; j < 4; j++) { mrow[fq][j] = -INFINITY; lsum[fq][j] = 0.f; }
    #pragma unroll
    for (int fd = 0; fd < 4; fd++) of[fq][fd] = (f32x4){0.f, 0.f, 0.f, 0.f};
  }

  for (int kt = 0; kt < SEQ / 64; kt++) {
    {
      const int i = t, r = i >> 3, c = i & 7;
      const int bc = 16 * (c ^ (r & 7));
      GLOAD16(kg + (size_t)(kt * 64 + r) * DMOD + (bc >> 1), Ks + (size_t)w * 512);
    }
    {
      const int i = 256 + t, r = i >> 3, c = i & 7;
      const int bc = 16 * (c ^ (r & 7));
      GLOAD16(kg + (size_t)(kt * 64 + r) * DMOD + (bc >> 1), Ks + 2048 + (size_t)w * 512);
    }
    {
      const int i = t, r = i >> 3, c = i & 7;
      const int bc = 16 * (c ^ (r & 7));
      GLOAD16(vg + (size_t)r * SEQ + kt * 64 + (bc >> 1), Vs + (size_t)w * 512);
    }
    {
      const int i = 256 + t, r = i >> 3, c = i & 7;
      const int bc = 16 * (c ^ (r & 7));
      GLOAD16(vg + (size_t)r * SEQ + kt * 64 + (bc >> 1), Vs + 2048 + (size_t)w * 512);
    }
    __syncthreads();

    f32x4 s[2][4];
    #pragma unroll
    for (int fq = 0; fq < 2; fq++)
      #pragma unroll
      for (int fk = 0; fk < 4; fk++) {
        f32x4 a = (f32x4){0.f, 0.f, 0.f, 0.f};
        #pragma unroll
        for (int kd = 0; kd < 2; kd++) {
          const int r = fk * 16 + rm;
          short8 bk = *(const short8*)((const char*)Ks + r * 128 + ((kd * 64 + g * 16) ^ ((r & 7) << 4)));
          a = MFMA16(aq[fq][kd], bk, a);
        }
        s[fq][fk] = a;
      }

    float pm[2][4];
    int grow = 0;
    #pragma unroll
    for (int fq = 0; fq < 2; fq++)
      #pragma unroll
      for (int j = 0; j < 4; j++) {
        float mx = fmaxf(fmaxf(s[fq][0][j], s[fq][1][j]), fmaxf(s[fq][2][j], s[fq][3][j]));
        #pragma unroll
        for (int mk = 1; mk < 16; mk <<= 1) mx = fmaxf(mx, __shfl_xor(mx, mk));
        pm[fq][j] = mx;
        grow |= (mx > mrow[fq][j] + 8.f);
      }
    if (__any(grow)) {
      #pragma unroll
      for (int fq = 0; fq < 2; fq++)
        #pragma unroll
        for (int j = 0; j < 4; j++) {
          const float mn = fmaxf(mrow[fq][j], pm[fq][j]);
          const float corr = __expf(mrow[fq][j] - mn);
          mrow[fq][j] = mn;
          lsum[fq][j] *= corr;
          #pragma unroll
          for (int fd = 0; fd < 4; fd++) of[fq][fd][j] *= corr;
        }
    }
    #pragma unroll
    for (int fq = 0; fq < 2; fq++)
      #pragma unroll
      for (int j = 0; j < 4; j++) {
        const int prow = (fq * 16 + g * 4 + j) * 72;
        float psum = 0.f;
        #pragma unroll
        for (int fk = 0; fk < 4; fk++) {
          const float p = __expf(s[fq][fk][j] - mrow[fq][j]);
          psum += p;
          Ps[w][prow + fk * 16 + rm] = f2bf(p);
        }
        lsum[fq][j] += psum;
      }

    #pragma unroll
    for (int fq = 0; fq < 2; fq++) {
      short8 pa0 = *(const short8*)&Ps[w][(fq * 16 + rm) * 72 + g * 8];
      short8 pa1 = *(const short8*)&Ps[w][(fq * 16 + rm) * 72 + 32 + g * 8];
      #pragma unroll
      for (int fd = 0; fd < 4; fd++) {
        const int r = fd * 16 + rm;
        const short8 vb0 = *(const short8*)((const char*)Vs + r * 128 + ((g * 16) ^ ((r & 7) << 4)));
        const short8 vb1 = *(const short8*)((const char*)Vs + r * 128 + ((64 + g * 16) ^ ((r & 7) << 4)));
        of[fq][fd] = MFMA16(pa0, vb0, of[fq][fd]);
        of[fq][fd] = MFMA16(pa1, vb1, of[fq][fd]);
      }
    }

    __syncthreads();
  }

  #pragma unroll
  for (int fq = 0; fq < 2; fq++)
    #pragma unroll
    for (int j = 0; j < 4; j++) {
      float ls = lsum[fq][j];
      #pragma unroll
      for (int mk = 1; mk < 16; mk <<= 1) ls += __shfl_xor(ls, mk);
      const float inv = 1.f / ls;
      const size_t q = (size_t)b * SEQ + qt * 128 + w * 32 + fq * 16 + g * 4 + j;
      #pragma unroll
      for (int fd = 0; fd < 4; fd++)
        ctx[q * DMOD + h * DHEAD + fd * 16 + rm] = f2bf(of[fq][fd][j] * inv);
    }
}

extern "C" void kernel_launch(void* const* d_in, const int* in_sizes, int n_in,
                              void* d_out, int out_size, void* d_ws, size_t ws_size,
                              hipStream_t stream) {
  const float* x_a   = (const float*)d_in[0];
  const float* x_b   = (const float*)d_in[1];
  const float* spk   = (const float*)d_in[2];
  const float* Wq    = (const float*)d_in[3];
  const float* bq    = (const float*)d_in[4];
  const float* Wk    = (const float*)d_in[5];
  const float* bk    = (const float*)d_in[6];
  const float* Wv    = (const float*)d_in[7];
  const float* bv    = (const float*)d_in[8];
  const float* Wo    = (const float*)d_in[9];
  const float* bo    = (const float*)d_in[10];
  const float* ln_g  = (const float*)d_in[11];
  const float* ln_b  = (const float*)d_in[12];
  const float* fln_g = (const float*)d_in[13];
  const float* fln_b = (const float*)d_in[14];
  const float* W1    = (const float*)d_in[15];
  const float* b1    = (const float*)d_in[16];
  const float* W2    = (const float*)d_in[17];
  const float* b2    = (const float*)d_in[18];
  float* out = (float*)d_out;           // also serves as the f32 x_b master (X)

  char* ws = (char*)d_ws;
  size_t o = 0;
  auto give = [&](size_t bytes) { char* p = ws + o; o += (bytes + 255) & ~(size_t)255; return p; };
  const size_t ACT2 = (size_t)NTOK * DMOD * 2;   // 32 MB bf16 activation

  unsigned short* qb16  = (unsigned short*)give(ACT2);
  unsigned short* kb16  = (unsigned short*)give(ACT2);
  unsigned short* vt16  = (unsigned short*)give(ACT2);       // V^T [b][h][d][l]
  unsigned short* ctx16 = (unsigned short*)give(ACT2);
  unsigned short* xa16  = (unsigned short*)give(ACT2);
  unsigned short* xbn16 = (unsigned short*)give(ACT2);
  float*          outf  = (float*)give((size_t)NTOK * DMOD * 4);   // 64 MB (residual stream)
  unsigned short* Wqt   = (unsigned short*)give((size_t)DMOD * DMOD * 2);
  unsigned short* Wkt   = (unsigned short*)give((size_t)DMOD * DMOD * 2);
  unsigned short* Wvt   = (unsigned short*)give((size_t)DMOD * DMOD * 2);
  unsigned short* Wot   = (unsigned short*)give((size_t)DMOD * DMOD * 2);
  unsigned short* W1t   = (unsigned short*)give((size_t)DMOD * DFFN * 2);
  unsigned short* W2t   = (unsigned short*)give((size_t)DMOD * DFFN * 2);
  float*          peb   = (float*)give((size_t)SEQ * DMOD * 4);
  unsigned short* inter = qb16;     // 128 MB span over qb16..ctx16 (dead during FFN)
  (void)ws_size; (void)in_sizes; (void)n_in; (void)out_size;

  const dim3 blk(256);
  const dim3 blk512(512);

  pe_kernel<<<dim3((SEQ * (DMOD / 2)) / 256), blk, 0, stream>>>(peb);
  const int nprep = (NTOK * DMOD / 4) / 256;
  prep_kernel<<<dim3(nprep, 1, 2), blk, 0, stream>>>(x_a, x_b, peb, spk, out, xa16, xbn16);

  const dim3 gQKV(DMOD / 256, NTOK / 128, 3);   // (4,128,3) = 1536 blocks
  const dim3 gWO (DMOD / 256, NTOK / 128);      // (4,128)   = 512
  const dim3 gW1 (DFFN / 256, NTOK / 128);      // (16,128)  = 2048
  const dim3 gW2 (DMOD / 256, NTOK / 128);      // (4,128)   = 512

  for (int i = 0; i < NLAY; i++) {
    wtrans_all<<<dim3(3072), blk, 0, stream>>>(Wq, Wk, Wv, Wo, W1, W2, i,
                                               Wqt, Wkt, Wvt, Wot, W1t, W2t);
    if (i != 0) {
      ln_kernel<1><<<dim3(NTOK), blk, 0, stream>>>(out, ln_g + (size_t)i * DMOD, ln_b + (size_t)i * DMOD, outf, xbn16);
    }
    gemm128<0><<<gQKV, blk512, 0, stream>>>(
        xbn16, xa16, Wqt, Wkt, Wvt,
        bq + (size_t)i * DMOD, bk + (size_t)i * DMOD, bv + (size_t)i * DMOD,
        nullptr, qb16, kb16, vt16, DMOD, DMOD);
    attn_mfma<<<dim3(SEQ / 128, NHEAD, BATCH), blk, 0, stream>>>(qb16, kb16, vt16, ctx16);
    if (i == 0) {
      gemm128<2><<<gWO, blk512, 0, stream>>>(
          ctx16, nullptr, Wot, nullptr, nullptr,
          bo + (size_t)i * DMOD, nullptr, nullptr, out, outf, nullptr, nullptr, DMOD, DMOD);
    } else {
      gemm128<3><<<gWO, blk512, 0, stream>>>(
          ctx16, nullptr, Wot, nullptr, nullptr,
          bo + (size_t)i * DMOD, nullptr, nullptr, nullptr, outf, nullptr, nullptr, DMOD, DMOD);
    }
    ln_kernel<0><<<dim3(NTOK), blk, 0, stream>>>(outf, fln_g + (size_t)i * DMOD, fln_b + (size_t)i * DMOD, nullptr, xbn16);
    gemm128<1><<<gW1, blk512, 0, stream>>>(
        xbn16, nullptr, W1t, nullptr, nullptr,
        b1 + (size_t)i * DFFN, nullptr, nullptr, nullptr, inter, nullptr, nullptr, DFFN, DMOD);
    gemm128<2><<<gW2, blk512, 0, stream>>>(
        inter, nullptr, W2t, nullptr, nullptr,
        b2 + (size_t)i * DMOD, nullptr, nullptr, outf, out, nullptr, nullptr, DMOD, DFFN);
  }
}

// Round 16
// 2342.267 us; speedup vs baseline: 1.2565x; 1.1218x over previous
//
#include <hip/hip_runtime.h>

// Problem dims (fixed)
#define BATCH 32
#define SEQ   512
#define DMOD  1024
#define DFFN  4096
#define NHEAD 16
#define DHEAD 64
#define NLAY  4
#define NTOK  (BATCH * SEQ)   // 16384

typedef __attribute__((ext_vector_type(8))) short short8;
typedef __attribute__((ext_vector_type(4))) float f32x4;
typedef unsigned int uint32;

__device__ __forceinline__ unsigned short f2bf(float f) {
  uint32 u = __builtin_bit_cast(uint32, f);
  u += 0x7fffu + ((u >> 16) & 1u);             // RNE
  return (unsigned short)(u >> 16);
}
__device__ __forceinline__ float bf2f(unsigned short u) {
  return __builtin_bit_cast(float, (uint32)u << 16);
}
__device__ __forceinline__ float gelu_f(float x) {
  float u = 0.7978845608028654f * (x + 0.044715f * x * x * x);
  u = fminf(fmaxf(u, -15.f), 15.f);
  float e = __expf(2.f * u);
  return 0.5f * x * (1.f + (e - 1.f) / (e + 1.f));
}

#define GLOAD16(g, l) __builtin_amdgcn_global_load_lds( \
    (const __attribute__((address_space(1))) void*)(g), \
    (__attribute__((address_space(3))) void*)(l), 16, 0, 0)

#define MFMA16(a, b, c) __builtin_amdgcn_mfma_f32_16x16x32_bf16((a), (b), (c), 0, 0, 0)

// ---------------- positional encoding table: pe[l][d], 512x1024 ----------------
__global__ __launch_bounds__(256) void pe_kernel(float* __restrict__ pe) {
  const int idx = blockIdx.x * 256 + threadIdx.x;   // 0 .. 512*512-1 (pairs)
  const int l = idx >> 9;
  const int i = idx & 511;
  const float dv = __expf((float)(2 * i) * (-9.210340371976184f / (float)DMOD));
  const float a = (float)l * dv;
  pe[(size_t)l * DMOD + 2 * i]     = sinf(a);
  pe[(size_t)l * DMOD + 2 * i + 1] = cosf(a);
}

// ---------------- x + pe + speaker -> bf16 (fused a/b via z) ----------------
__global__ __launch_bounds__(256) void prep_kernel(
    const float* __restrict__ xa, const float* __restrict__ xb,
    const float* __restrict__ pe, const float* __restrict__ spk,
    unsigned short* __restrict__ oa16, unsigned short* __restrict__ ob16)
{
  const int z = blockIdx.z;
  const float* x = z ? xb : xa;
  unsigned short* o16 = z ? ob16 : oa16;
  const size_t id4 = (size_t)blockIdx.x * 256 + threadIdx.x;  // over B*L*D/4
  const size_t e = id4 * 4;
  const int b  = (int)(e >> 19);
  const int ld = (int)(e & ((1u << 19) - 1));
  const int d  = (int)(e & 1023);
  float4 xv = ((const float4*)x)[id4];
  float4 pv = ((const float4*)pe)[ld >> 2];
  float4 sv = ((const float4*)spk)[(size_t)b * 256 + (d >> 2)];
  ushort4 h;
  h.x = f2bf(xv.x + pv.x + sv.x);
  h.y = f2bf(xv.y + pv.y + sv.y);
  h.z = f2bf(xv.z + pv.z + sv.z);
  h.w = f2bf(xv.w + pv.w + sv.w);
  ((ushort4*)o16)[id4] = h;
}

// ---------------- merged per-layer weight transpose: all 6 weights ----------------
__global__ __launch_bounds__(256) void wtrans_all(
    const float* __restrict__ Wq, const float* __restrict__ Wk,
    const float* __restrict__ Wv, const float* __restrict__ Wo,
    const float* __restrict__ W1, const float* __restrict__ W2, int layer,
    unsigned short* __restrict__ Wqt, unsigned short* __restrict__ Wkt,
    unsigned short* __restrict__ Wvt, unsigned short* __restrict__ Wot,
    unsigned short* __restrict__ W1t, unsigned short* __restrict__ W2t)
{
  __shared__ float tile[64][65];
  const int bid = blockIdx.x;
  const float* W; unsigned short* Wt; int K, N, bx, by;
  if (bid < 1024) {
    const int which = bid >> 8, r = bid & 255;
    bx = r & 15; by = r >> 4; K = DMOD; N = DMOD;
    const size_t off = (size_t)layer * DMOD * DMOD;
    W  = (which == 0 ? Wq : which == 1 ? Wk : which == 2 ? Wv : Wo) + off;
    Wt = (which == 0 ? Wqt : which == 1 ? Wkt : which == 2 ? Wvt : Wot);
  } else if (bid < 2048) {
    const int r = bid - 1024;
    bx = r & 63; by = r >> 6; K = DMOD; N = DFFN;
    W = W1 + (size_t)layer * DMOD * DFFN; Wt = W1t;
  } else {
    const int r = bid - 2048;
    bx = r & 15; by = r >> 4; K = DFFN; N = DMOD;
    W = W2 + (size_t)layer * DMOD * DFFN; Wt = W2t;
  }
  const int n0 = bx * 64, k0 = by * 64;
  const int tx = threadIdx.x & 63, ty = threadIdx.x >> 6;
  #pragma unroll
  for (int i = 0; i < 16; i++) {
    int r = ty + 4 * i;
    tile[r][tx] = W[(size_t)(k0 + r) * N + n0 + tx];
  }
  __syncthreads();
  #pragma unroll
  for (int i = 0; i < 16; i++) {
    int rn = ty + 4 * i;
    Wt[(size_t)(n0 + rn) * K + k0 + tx] = f2bf(tile[tx][rn]);
  }
}

// ---------------- LayerNorm: one block per row; BF16IN selects input dtype ------
template<int BF16IN>
__global__ __launch_bounds__(256) void ln_kernel(
    const void* __restrict__ xin, const float* __restrict__ g,
    const float* __restrict__ bta, unsigned short* __restrict__ o16)
{
  const int row = blockIdx.x;
  const int t = threadIdx.x;
  float4 v;
  if (BF16IN) {
    ushort4 u = ((const ushort4*)((const unsigned short*)xin + (size_t)row * DMOD))[t];
    v.x = bf2f(u.x); v.y = bf2f(u.y); v.z = bf2f(u.z); v.w = bf2f(u.w);
  } else {
    v = ((const float4*)((const float*)xin + (size_t)row * DMOD))[t];
  }
  float s  = v.x + v.y + v.z + v.w;
  float s2 = v.x*v.x + v.y*v.y + v.z*v.z + v.w*v.w;
  #pragma unroll
  for (int off = 32; off > 0; off >>= 1) {
    s  += __shfl_down(s, off);
    s2 += __shfl_down(s2, off);
  }
  __shared__ float red[8];
  if ((t & 63) == 0) { red[(t >> 6) * 2] = s; red[(t >> 6) * 2 + 1] = s2; }
  __syncthreads();
  const float sum  = red[0] + red[2] + red[4] + red[6];
  const float sum2 = red[1] + red[3] + red[5] + red[7];
  const float mean = sum * (1.f / (float)DMOD);
  const float var  = sum2 * (1.f / (float)DMOD) - mean * mean;
  const float rstd = rsqrtf(var + 1e-6f);
  const float4 gg = ((const float4*)g)[t];
  const float4 bb = ((const float4*)bta)[t];
  ushort4 h;
  h.x = f2bf((v.x - mean) * rstd * gg.x + bb.x);
  h.y = f2bf((v.y - mean) * rstd * gg.y + bb.y);
  h.z = f2bf((v.z - mean) * rstd * gg.z + bb.z);
  h.w = f2bf((v.w - mean) * rstd * gg.w + bb.w);
  ((ushort4*)o16)[(size_t)row * 256 + t] = h;
}

// ---------------- GEMM 128x256, 8 waves, BK=64 single-buffer (ROUND-15 core) -----
// 64 KB LDS; epilogue uses 8 private wave slabs -> zero epilogue barriers.
// Swizzle for 128B rows: 16B-chunk idx (3b) ^ (row&7), both sides.
// launch_bounds(512,4): round-9 lesson — never raise min-waves blind.
// MODE 0: fused QKV via grid.z: z=0 Q (bias,*0.125,bf16), z=1 K (bias,bf16),
//         z=2 V (bias, bf16 V^T [b][ch][l]).  A = z?A1:A0.
// MODE 1: bias+gelu->bf16 (W1).
// MODE 4: bias + IN-PLACE bf16 add (Wo: outp += acc+bias, slab bounce + RMW).
// MODE 5: bias + res(bf16) -> f32 (W2: out = acc + bias + bf2f(res16)).
template<int MODE>
__global__ __launch_bounds__(512, 4) void gemm128(
    const unsigned short* __restrict__ A0, const unsigned short* __restrict__ A1,
    const unsigned short* __restrict__ B0, const unsigned short* __restrict__ B1,
    const unsigned short* __restrict__ B2,
    const float* __restrict__ bias0, const float* __restrict__ bias1,
    const float* __restrict__ bias2, const void* __restrict__ resv,
    void* out0, void* out1, void* out2, int N, int K)
{
  __shared__ unsigned short Sh[32768];   // 64 KB: stage As[0,8192) Bs[8192,24576)
  unsigned short* As = Sh;               // 128 rows x 64 hw (128 B/row)
  unsigned short* Bs = Sh + 8192;        // 256 rows x 64 hw
  const int t = threadIdx.x;
  const int lane = t & 63, w = t >> 6;
  const int wm = w >> 2, wn = w & 3;     // 2(M) x 4(N) wave grid; wave owns 64x64
  const int g = lane >> 4, rm = lane & 15;

  // XCD-aware bijective remap over the whole (possibly 3D) grid
  const int gx = gridDim.x, gy = gridDim.y;
  const int nwg = gx * gy * gridDim.z;
  const int hid = (blockIdx.z * gy + blockIdx.y) * gx + blockIdx.x;
  const int wid = (hid & 7) * (nwg >> 3) + (hid >> 3);
  const int bx = wid % gx;
  const int rest = wid / gx;
  const int by = rest % gy;
  const int z  = rest / gy;              // 0 for 2D grids

  const unsigned short* A  = (MODE == 0 && z) ? A1 : A0;
  const unsigned short* Bt = (MODE == 0) ? (z == 0 ? B0 : z == 1 ? B1 : B2) : B0;
  const float* bias        = (MODE == 0) ? (z == 0 ? bias0 : z == 1 ? bias1 : bias2) : bias0;
  void* outp               = (MODE == 0) ? (z == 0 ? out0 : z == 1 ? out1 : out2) : out0;

  const size_t tm = (size_t)by * 128;
  const size_t tn = (size_t)bx * 256;

  // staging per K-tile: A 1024 16B-chunks (2/thread), B 2048 (4/thread).
  const int ia0 = t, ia1 = 512 + t;
  const int ra0 = ia0 >> 3, ra1 = ia1 >> 3;
  const int ca0 = 8 * ((ia0 & 7) ^ (ra0 & 7));
  const int ca1 = 8 * ((ia1 & 7) ^ (ra1 & 7));
  const int ib0 = t, ib1 = 512 + t, ib2 = 1024 + t, ib3 = 1536 + t;
  const int rb0 = ib0 >> 3, rb1 = ib1 >> 3, rb2 = ib2 >> 3, rb3 = ib3 >> 3;
  const int cb0 = 8 * ((ib0 & 7) ^ (rb0 & 7));
  const int cb1 = 8 * ((ib1 & 7) ^ (rb1 & 7));
  const int cb2 = 8 * ((ib2 & 7) ^ (rb2 & 7));
  const int cb3 = 8 * ((ib3 & 7) ^ (rb3 & 7));
  const unsigned short* Ab0 = A + (tm + ra0) * (size_t)K + ca0;
  const unsigned short* Ab1 = A + (tm + ra1) * (size_t)K + ca1;
  const unsigned short* Bb0 = Bt + (tn + rb0) * (size_t)K + cb0;
  const unsigned short* Bb1 = Bt + (tn + rb1) * (size_t)K + cb1;
  const unsigned short* Bb2 = Bt + (tn + rb2) * (size_t)K + cb2;
  const unsigned short* Bb3 = Bt + (tn + rb3) * (size_t)K + cb3;

  // swizzled fragment read offsets (bytes), kd=0; kd=1 is ^64
  int aoff[4], boff[4];
  #pragma unroll
  for (int fm = 0; fm < 4; fm++) {
    const int r = wm * 64 + fm * 16 + rm;
    aoff[fm] = r * 128 + ((g ^ (r & 7)) * 16);
  }
  #pragma unroll
  for (int fn = 0; fn < 4; fn++) {
    const int r = wn * 64 + fn * 16 + rm;
    boff[fn] = r * 128 + ((g ^ (r & 7)) * 16);
  }

  f32x4 acc[4][4];
  #pragma unroll
  for (int i = 0; i < 4; i++)
    #pragma unroll
    for (int j = 0; j < 4; j++)
      acc[i][j] = (f32x4){0.f, 0.f, 0.f, 0.f};

  const int nt = K >> 6;   // BK = 64
  for (int kt = 0; kt < nt; kt++) {
    const int k0 = kt * 64;
    GLOAD16(Ab0 + k0, &As[ia0 * 8]);
    GLOAD16(Ab1 + k0, &As[ia1 * 8]);
    GLOAD16(Bb0 + k0, &Bs[ib0 * 8]);
    GLOAD16(Bb1 + k0, &Bs[ib1 * 8]);
    GLOAD16(Bb2 + k0, &Bs[ib2 * 8]);
    GLOAD16(Bb3 + k0, &Bs[ib3 * 8]);
    __syncthreads();
    {
      short8 a[4], b[4];
      #pragma unroll
      for (int fm = 0; fm < 4; fm++) a[fm] = *(const short8*)((const char*)As + aoff[fm]);
      #pragma unroll
      for (int fn = 0; fn < 4; fn++) b[fn] = *(const short8*)((const char*)Bs + boff[fn]);
      #pragma unroll
      for (int fm = 0; fm < 4; fm++)
        #pragma unroll
        for (int fn = 0; fn < 4; fn++)
          acc[fm][fn] = MFMA16(a[fm], b[fn], acc[fm][fn]);
    }
    {
      short8 a[4], b[4];
      #pragma unroll
      for (int fm = 0; fm < 4; fm++) a[fm] = *(const short8*)((const char*)As + (aoff[fm] ^ 64));
      #pragma unroll
      for (int fn = 0; fn < 4; fn++) b[fn] = *(const short8*)((const char*)Bs + (boff[fn] ^ 64));
      #pragma unroll
      for (int fm = 0; fm < 4; fm++)
        #pragma unroll
        for (int fn = 0; fn < 4; fn++)
          acc[fm][fn] = MFMA16(a[fm], b[fn], acc[fm][fn]);
    }
    __syncthreads();
  }
  // After the final barrier all LDS reads are done; each wave uses its OWN
  // 8 KB slab (Sh + w*4096 hw) for bf16 bounces -> no epilogue barriers.

  if (MODE == 5) {
    const unsigned short* res16 = (const unsigned short*)resv;
    #pragma unroll
    for (int fn = 0; fn < 4; fn++) {
      const size_t gcol = tn + wn * 64 + fn * 16 + rm;
      const float bc = bias[gcol];
      #pragma unroll
      for (int fm = 0; fm < 4; fm++) {
        #pragma unroll
        for (int r = 0; r < 4; r++) {
          const size_t grow = tm + wm * 64 + fm * 16 + g * 4 + r;
          const size_t off = grow * (size_t)N + gcol;
          ((float*)outp)[off] = acc[fm][fn][r] + bc + bf2f(res16[off]);
        }
      }
    }
  } else if (MODE == 4) {
    // bf16 in-place add: bounce acc+bias to private slab, then coalesced RMW
    unsigned short* eb = Sh + w * 4096;
    #pragma unroll
    for (int fn = 0; fn < 4; fn++) {
      const float bc = bias[tn + wn * 64 + fn * 16 + rm];
      #pragma unroll
      for (int fm = 0; fm < 4; fm++)
        #pragma unroll
        for (int r = 0; r < 4; r++) {
          const int lr = fm * 16 + g * 4 + r;
          const int lc = fn * 16 + rm;
          eb[lr * 64 + (lc ^ (g << 4))] = f2bf(acc[fm][fn][r] + bc);
        }
    }
    #pragma unroll
    for (int pass = 0; pass < 8; pass++) {
      const int lr = pass * 8 + (lane >> 3);
      const int lc8 = (lane & 7) * 8;
      const int q = (lr >> 2) & 3;
      short8 nv = *(const short8*)&eb[lr * 64 + (lc8 ^ (q << 4))];
      unsigned short* gp = (unsigned short*)outp +
                           (tm + wm * 64 + lr) * (size_t)N + tn + wn * 64 + lc8;
      short8 ov = *(const short8*)gp;
      short8 rv;
      #pragma unroll
      for (int j = 0; j < 8; j++)
        rv[j] = (short)f2bf(bf2f((unsigned short)nv[j]) + bf2f((unsigned short)ov[j]));
      *(short8*)gp = rv;
    }
  } else if (MODE == 0) {
    unsigned short* eb = Sh + w * 4096;    // private slab
    if (z == 2) {
      // V^T slab [64 ch][64 tok]
      #pragma unroll
      for (int fn = 0; fn < 4; fn++) {
        const float bc = bias[tn + wn * 64 + fn * 16 + rm];
        #pragma unroll
        for (int fm = 0; fm < 4; fm++)
          #pragma unroll
          for (int r = 0; r < 4; r++) {
            const int tok = fm * 16 + g * 4 + r;
            const int ch  = fn * 16 + rm;
            eb[ch * 64 + (tok ^ ((ch & 7) << 3))] = f2bf(acc[fm][fn][r] + bc);
          }
      }
      const int tok0 = (int)tm + wm * 64;
      const int bb = tok0 >> 9, l0 = tok0 & 511;
      #pragma unroll
      for (int pass = 0; pass < 8; pass++) {
        const int ch = pass * 8 + (lane >> 3);
        const int t8 = (lane & 7) * 8;
        short8 vv = *(const short8*)&eb[ch * 64 + (t8 ^ ((ch & 7) << 3))];
        *(short8*)((unsigned short*)outp +
                   ((size_t)bb * 1024 + tn + wn * 64 + ch) * 512 + l0 + t8) = vv;
      }
    } else {
      // row-major slab [64 rows][64 cols]
      #pragma unroll
      for (int fn = 0; fn < 4; fn++) {
        const float bc = bias[tn + wn * 64 + fn * 16 + rm];
        #pragma unroll
        for (int fm = 0; fm < 4; fm++)
          #pragma unroll
          for (int r = 0; r < 4; r++) {
            float v = acc[fm][fn][r] + bc;
            if (z == 0) v *= 0.125f;
            const int lr = fm * 16 + g * 4 + r;
            const int lc = fn * 16 + rm;
            eb[lr * 64 + (lc ^ (g << 4))] = f2bf(v);
          }
      }
      #pragma unroll
      for (int pass = 0; pass < 8; pass++) {
        const int lr = pass * 8 + (lane >> 3);
        const int lc8 = (lane & 7) * 8;
        const int q = (lr >> 2) & 3;
        short8 vv = *(const short8*)&eb[lr * 64 + (lc8 ^ (q << 4))];
        *(short8*)((unsigned short*)outp +
                   (tm + wm * 64 + lr) * (size_t)N + tn + wn * 64 + lc8) = vv;
      }
    }
  } else {
    // MODE 1: gelu bf16 row-major, private slab
    unsigned short* eb = Sh + w * 4096;
    #pragma unroll
    for (int fn = 0; fn < 4; fn++) {
      const float bc = bias[tn + wn * 64 + fn * 16 + rm];
      #pragma unroll
      for (int fm = 0; fm < 4; fm++)
        #pragma unroll
        for (int r = 0; r < 4; r++) {
          const int lr = fm * 16 + g * 4 + r;
          const int lc = fn * 16 + rm;
          eb[lr * 64 + (lc ^ (g << 4))] = f2bf(gelu_f(acc[fm][fn][r] + bc));
        }
    }
    #pragma unroll
    for (int pass = 0; pass < 8; pass++) {
      const int lr = pass * 8 + (lane >> 3);
      const int lc8 = (lane & 7) * 8;
      const int q = (lr >> 2) & 3;
      short8 vv = *(const short8*)&eb[lr * 64 + (lc8 ^ (q << 4))];
      *(short8*)((unsigned short*)outp +
                 (tm + wm * 64 + lr) * (size_t)N + tn + wn * 64 + lc8) = vv;
    }
  }
}

// ---------------- MFMA flash attention: KVBLK=64, Q-region reuse (ROUND-14) -----
__global__ __launch_bounds__(256) void attn_mfma(
    const unsigned short* __restrict__ qb, const unsigned short* __restrict__ kb,
    const unsigned short* __restrict__ vt, unsigned short* __restrict__ ctx)
{
  __shared__ unsigned short Sh[8192];          // 16 KB: Q(128x64hw) -> K(64x64)|V(64x64)
  __shared__ unsigned short Ps[4][32 * 72];    // 18 KB
  unsigned short* Ks = Sh;
  unsigned short* Vs = Sh + 4096;
  const int t = threadIdx.x;
  const int lane = t & 63, w = t >> 6;
  const int g = lane >> 4, rm = lane & 15;
  const int qt = blockIdx.x, h = blockIdx.y, b = blockIdx.z;

  const unsigned short* qg = qb + ((size_t)(b * SEQ + qt * 128)) * DMOD + h * DHEAD;
  const unsigned short* kg = kb + ((size_t)(b * SEQ)) * DMOD + h * DHEAD;
  const unsigned short* vg = vt + ((size_t)(b * NHEAD + h)) * DHEAD * SEQ;  // [64][512]

  #pragma unroll
  for (int ii = 0; ii < 4; ii++) {
    const int i = ii * 256 + t;
    const int r = i >> 3, c = i & 7;
    const int bc = 16 * (c ^ (r & 7));
    GLOAD16(qg + (size_t)r * DMOD + (bc >> 1), Sh + (size_t)(ii * 256 + w * 64) * 8);
  }
  __syncthreads();

  short8 aq[2][2];
  #pragma unroll
  for (int fq = 0; fq < 2; fq++)
    #pragma unroll
    for (int kd = 0; kd < 2; kd++) {
      const int r = w * 32 + fq * 16 + rm;
      aq[fq][kd] = *(const short8*)((const char*)Sh + r * 128 + ((kd * 64 + g * 16) ^ ((r & 7) << 4)));
    }
  __syncthreads();   // all aq reads done before K/V staging overwrites Q region

  float mrow[2][4], lsum[2][4];
  f32x4 of[2][4];
  #pragma unroll
  for (int fq = 0; fq < 2; fq++) {
    #pragma unroll
    for (int j = 0; j < 4; j++) { mrow[fq][j] = -INFINITY; lsum[fq][j] = 0.f; }
    #pragma unroll
    for (int fd = 0; fd < 4; fd++) of[fq][fd] = (f32x4){0.f, 0.f, 0.f, 0.f};
  }

  for (int kt = 0; kt < SEQ / 64; kt++) {
    {
      const int i = t, r = i >> 3, c = i & 7;
      const int bc = 16 * (c ^ (r & 7));
      GLOAD16(kg + (size_t)(kt * 64 + r) * DMOD + (bc >> 1), Ks + (size_t)w * 512);
    }
    {
      const int i = 256 + t, r = i >> 3, c = i & 7;
      const int bc = 16 * (c ^ (r & 7));
      GLOAD16(kg + (size_t)(kt * 64 + r) * DMOD + (bc >> 1), Ks + 2048 + (size_t)w * 512);
    }
    {
      const int i = t, r = i >> 3, c = i & 7;
      const int bc = 16 * (c ^ (r & 7));
      GLOAD16(vg + (size_t)r * SEQ + kt * 64 + (bc >> 1), Vs + (size_t)w * 512);
    }
    {
      const int i = 256 + t, r = i >> 3, c = i & 7;
      const int bc = 16 * (c ^ (r & 7));
      GLOAD16(vg + (size_t)r * SEQ + kt * 64 + (bc >> 1), Vs + 2048 + (size_t)w * 512);
    }
    __syncthreads();

    f32x4 s[2][4];
    #pragma unroll
    for (int fq = 0; fq < 2; fq++)
      #pragma unroll
      for (int fk = 0; fk < 4; fk++) {
        f32x4 a = (f32x4){0.f, 0.f, 0.f, 0.f};
        #pragma unroll
        for (int kd = 0; kd < 2; kd++) {
          const int r = fk * 16 + rm;
          short8 bk = *(const short8*)((const char*)Ks + r * 128 + ((kd * 64 + g * 16) ^ ((r & 7) << 4)));
          a = MFMA16(aq[fq][kd], bk, a);
        }
        s[fq][fk] = a;
      }

    float pm[2][4];
    int grow = 0;
    #pragma unroll
    for (int fq = 0; fq < 2; fq++)
      #pragma unroll
      for (int j = 0; j < 4; j++) {
        float mx = fmaxf(fmaxf(s[fq][0][j], s[fq][1][j]), fmaxf(s[fq][2][j], s[fq][3][j]));
        #pragma unroll
        for (int mk = 1; mk < 16; mk <<= 1) mx = fmaxf(mx, __shfl_xor(mx, mk));
        pm[fq][j] = mx;
        grow |= (mx > mrow[fq][j] + 8.f);
      }
    if (__any(grow)) {
      #pragma unroll
      for (int fq = 0; fq < 2; fq++)
        #pragma unroll
        for (int j = 0; j < 4; j++) {
          const float mn = fmaxf(mrow[fq][j], pm[fq][j]);
          const float corr = __expf(mrow[fq][j] - mn);
          mrow[fq][j] = mn;
          lsum[fq][j] *= corr;
          #pragma unroll
          for (int fd = 0; fd < 4; fd++) of[fq][fd][j] *= corr;
        }
    }
    #pragma unroll
    for (int fq = 0; fq < 2; fq++)
      #pragma unroll
      for (int j = 0; j < 4; j++) {
        const int prow = (fq * 16 + g * 4 + j) * 72;
        float psum = 0.f;
        #pragma unroll
        for (int fk = 0; fk < 4; fk++) {
          const float p = __expf(s[fq][fk][j] - mrow[fq][j]);
          psum += p;
          Ps[w][prow + fk * 16 + rm] = f2bf(p);
        }
        lsum[fq][j] += psum;
      }

    #pragma unroll
    for (int fq = 0; fq < 2; fq++) {
      short8 pa0 = *(const short8*)&Ps[w][(fq * 16 + rm) * 72 + g * 8];
      short8 pa1 = *(const short8*)&Ps[w][(fq * 16 + rm) * 72 + 32 + g * 8];
      #pragma unroll
      for (int fd = 0; fd < 4; fd++) {
        const int r = fd * 16 + rm;
        const short8 vb0 = *(const short8*)((const char*)Vs + r * 128 + ((g * 16) ^ ((r & 7) << 4)));
        const short8 vb1 = *(const short8*)((const char*)Vs + r * 128 + ((64 + g * 16) ^ ((r & 7) << 4)));
        of[fq][fd] = MFMA16(pa0, vb0, of[fq][fd]);
        of[fq][fd] = MFMA16(pa1, vb1, of[fq][fd]);
      }
    }

    __syncthreads();
  }

  #pragma unroll
  for (int fq = 0; fq < 2; fq++)
    #pragma unroll
    for (int j = 0; j < 4; j++) {
      float ls = lsum[fq][j];
      #pragma unroll
      for (int mk = 1; mk < 16; mk <<= 1) ls += __shfl_xor(ls, mk);
      const float inv = 1.f / ls;
      const size_t q = (size_t)b * SEQ + qt * 128 + w * 32 + fq * 16 + g * 4 + j;
      #pragma unroll
      for (int fd = 0; fd < 4; fd++)
        ctx[q * DMOD + h * DHEAD + fd * 16 + rm] = f2bf(of[fq][fd][j] * inv);
    }
}

extern "C" void kernel_launch(void* const* d_in, const int* in_sizes, int n_in,
                              void* d_out, int out_size, void* d_ws, size_t ws_size,
                              hipStream_t stream) {
  const float* x_a   = (const float*)d_in[0];
  const float* x_b   = (const float*)d_in[1];
  const float* spk   = (const float*)d_in[2];
  const float* Wq    = (const float*)d_in[3];
  const float* bq    = (const float*)d_in[4];
  const float* Wk    = (const float*)d_in[5];
  const float* bk    = (const float*)d_in[6];
  const float* Wv    = (const float*)d_in[7];
  const float* bv    = (const float*)d_in[8];
  const float* Wo    = (const float*)d_in[9];
  const float* bo    = (const float*)d_in[10];
  const float* ln_g  = (const float*)d_in[11];
  const float* ln_b  = (const float*)d_in[12];
  const float* fln_g = (const float*)d_in[13];
  const float* fln_b = (const float*)d_in[14];
  const float* W1    = (const float*)d_in[15];
  const float* b1    = (const float*)d_in[16];
  const float* W2    = (const float*)d_in[17];
  const float* b2    = (const float*)d_in[18];
  float* out = (float*)d_out;           // f32 x_b master (written by W2 each layer)

  char* ws = (char*)d_ws;
  size_t o = 0;
  auto give = [&](size_t bytes) { char* p = ws + o; o += (bytes + 255) & ~(size_t)255; return p; };
  const size_t ACT2 = (size_t)NTOK * DMOD * 2;   // 32 MB bf16 activation

  // qb,kb,vt,ctx contiguous (128 MB) -> `inter` aliases the span during FFN.
  unsigned short* qb16  = (unsigned short*)give(ACT2);
  unsigned short* kb16  = (unsigned short*)give(ACT2);
  unsigned short* vt16  = (unsigned short*)give(ACT2);       // V^T [b][h][d][l]
  unsigned short* ctx16 = (unsigned short*)give(ACT2);
  unsigned short* xa16  = (unsigned short*)give(ACT2);
  unsigned short* xbn16 = (unsigned short*)give(ACT2);       // XN / bf16 residual stream
  unsigned short* xn2   = (unsigned short*)give(ACT2);       // FFN-LN output
  unsigned short* Wqt   = (unsigned short*)give((size_t)DMOD * DMOD * 2);
  unsigned short* Wkt   = (unsigned short*)give((size_t)DMOD * DMOD * 2);
  unsigned short* Wvt   = (unsigned short*)give((size_t)DMOD * DMOD * 2);
  unsigned short* Wot   = (unsigned short*)give((size_t)DMOD * DMOD * 2);
  unsigned short* W1t   = (unsigned short*)give((size_t)DMOD * DFFN * 2);
  unsigned short* W2t   = (unsigned short*)give((size_t)DMOD * DFFN * 2);
  float*          peb   = (float*)give((size_t)SEQ * DMOD * 4);
  unsigned short* inter = qb16;     // 128 MB span over qb16..ctx16 (dead during FFN)
  (void)ws_size; (void)in_sizes; (void)n_in; (void)out_size;

  const dim3 blk(256);
  const dim3 blk512(512);

  pe_kernel<<<dim3((SEQ * (DMOD / 2)) / 256), blk, 0, stream>>>(peb);
  const int nprep = (NTOK * DMOD / 4) / 256;
  prep_kernel<<<dim3(nprep, 1, 2), blk, 0, stream>>>(x_a, x_b, peb, spk, xa16, xbn16);

  const dim3 gQKV(DMOD / 256, NTOK / 128, 3);   // (4,128,3) = 1536 blocks
  const dim3 gWO (DMOD / 256, NTOK / 128);      // (4,128)   = 512
  const dim3 gW1 (DFFN / 256, NTOK / 128);      // (16,128)  = 2048
  const dim3 gW2 (DMOD / 256, NTOK / 128);      // (4,128)   = 512

  for (int i = 0; i < NLAY; i++) {
    wtrans_all<<<dim3(3072), blk, 0, stream>>>(Wq, Wk, Wv, Wo, W1, W2, i,
                                               Wqt, Wkt, Wvt, Wot, W1t, W2t);
    if (i != 0) {
      // XN = LN(x_b master) -> bf16 (residual stream AND Q input)
      ln_kernel<0><<<dim3(NTOK), blk, 0, stream>>>(out, ln_g + (size_t)i * DMOD, ln_b + (size_t)i * DMOD, xbn16);
    }
    gemm128<0><<<gQKV, blk512, 0, stream>>>(
        xbn16, xa16, Wqt, Wkt, Wvt,
        bq + (size_t)i * DMOD, bk + (size_t)i * DMOD, bv + (size_t)i * DMOD,
        nullptr, qb16, kb16, vt16, DMOD, DMOD);
    attn_mfma<<<dim3(SEQ / 128, NHEAD, BATCH), blk, 0, stream>>>(qb16, kb16, vt16, ctx16);
    // out_res (bf16) = ctx @ Wo + bo + XN   (in-place into xbn16)
    gemm128<4><<<gWO, blk512, 0, stream>>>(
        ctx16, nullptr, Wot, nullptr, nullptr,
        bo + (size_t)i * DMOD, nullptr, nullptr, nullptr, xbn16, nullptr, nullptr, DMOD, DMOD);
    // xn2 = LN(out_res)
    ln_kernel<1><<<dim3(NTOK), blk, 0, stream>>>(xbn16, fln_g + (size_t)i * DMOD, fln_b + (size_t)i * DMOD, xn2);
    gemm128<1><<<gW1, blk512, 0, stream>>>(
        xn2, nullptr, W1t, nullptr, nullptr,
        b1 + (size_t)i * DFFN, nullptr, nullptr, nullptr, inter, nullptr, nullptr, DFFN, DMOD);
    // x_b master (f32) = inter @ W2 + b2 + out_res(bf16)
    gemm128<5><<<gW2, blk512, 0, stream>>>(
        inter, nullptr, W2t, nullptr, nullptr,
        b2 + (size_t)i * DMOD, nullptr, nullptr, xbn16, out, nullptr, nullptr, DMOD, DFFN);
  }
}

// Round 17
// 2196.139 us; speedup vs baseline: 1.3401x; 1.0665x over previous
//
#include <hip/hip_runtime.h>

// Problem dims (fixed)
#define BATCH 32
#define SEQ   512
#define DMOD  1024
#define DFFN  4096
#define NHEAD 16
#define DHEAD 64
#define NLAY  4
#define NTOK  (BATCH * SEQ)   // 16384

typedef __attribute__((ext_vector_type(8))) short short8;
typedef __attribute__((ext_vector_type(4))) float f32x4;
typedef unsigned int uint32;

__device__ __forceinline__ unsigned short f2bf(float f) {
  uint32 u = __builtin_bit_cast(uint32, f);
  u += 0x7fffu + ((u >> 16) & 1u);             // RNE
  return (unsigned short)(u >> 16);
}
__device__ __forceinline__ float bf2f(unsigned short u) {
  return __builtin_bit_cast(float, (uint32)u << 16);
}
__device__ __forceinline__ float gelu_f(float x) {
  float u = 0.7978845608028654f * (x + 0.044715f * x * x * x);
  u = fminf(fmaxf(u, -15.f), 15.f);
  float e = __expf(2.f * u);
  return 0.5f * x * (1.f + (e - 1.f) / (e + 1.f));
}

#define GLOAD16(g, l) __builtin_amdgcn_global_load_lds( \
    (const __attribute__((address_space(1))) void*)(g), \
    (__attribute__((address_space(3))) void*)(l), 16, 0, 0)

#define MFMA16(a, b, c) __builtin_amdgcn_mfma_f32_16x16x32_bf16((a), (b), (c), 0, 0, 0)

// ---------------- positional encoding table: pe[l][d], 512x1024 ----------------
__global__ __launch_bounds__(256) void pe_kernel(float* __restrict__ pe) {
  const int idx = blockIdx.x * 256 + threadIdx.x;   // 0 .. 512*512-1 (pairs)
  const int l = idx >> 9;
  const int i = idx & 511;
  const float dv = __expf((float)(2 * i) * (-9.210340371976184f / (float)DMOD));
  const float a = (float)l * dv;
  pe[(size_t)l * DMOD + 2 * i]     = sinf(a);
  pe[(size_t)l * DMOD + 2 * i + 1] = cosf(a);
}

// ---------------- x + pe + speaker -> bf16 (fused a/b via z) ----------------
__global__ __launch_bounds__(256) void prep_kernel(
    const float* __restrict__ xa, const float* __restrict__ xb,
    const float* __restrict__ pe, const float* __restrict__ spk,
    unsigned short* __restrict__ oa16, unsigned short* __restrict__ ob16)
{
  const int z = blockIdx.z;
  const float* x = z ? xb : xa;
  unsigned short* o16 = z ? ob16 : oa16;
  const size_t id4 = (size_t)blockIdx.x * 256 + threadIdx.x;  // over B*L*D/4
  const size_t e = id4 * 4;
  const int b  = (int)(e >> 19);
  const int ld = (int)(e & ((1u << 19) - 1));
  const int d  = (int)(e & 1023);
  float4 xv = ((const float4*)x)[id4];
  float4 pv = ((const float4*)pe)[ld >> 2];
  float4 sv = ((const float4*)spk)[(size_t)b * 256 + (d >> 2)];
  ushort4 h;
  h.x = f2bf(xv.x + pv.x + sv.x);
  h.y = f2bf(xv.y + pv.y + sv.y);
  h.z = f2bf(xv.z + pv.z + sv.z);
  h.w = f2bf(xv.w + pv.w + sv.w);
  ((ushort4*)o16)[id4] = h;
}

// ---------------- merged per-layer weight transpose: all 6 weights ----------------
__global__ __launch_bounds__(256) void wtrans_all(
    const float* __restrict__ Wq, const float* __restrict__ Wk,
    const float* __restrict__ Wv, const float* __restrict__ Wo,
    const float* __restrict__ W1, const float* __restrict__ W2, int layer,
    unsigned short* __restrict__ Wqt, unsigned short* __restrict__ Wkt,
    unsigned short* __restrict__ Wvt, unsigned short* __restrict__ Wot,
    unsigned short* __restrict__ W1t, unsigned short* __restrict__ W2t)
{
  __shared__ float tile[64][65];
  const int bid = blockIdx.x;
  const float* W; unsigned short* Wt; int K, N, bx, by;
  if (bid < 1024) {
    const int which = bid >> 8, r = bid & 255;
    bx = r & 15; by = r >> 4; K = DMOD; N = DMOD;
    const size_t off = (size_t)layer * DMOD * DMOD;
    W  = (which == 0 ? Wq : which == 1 ? Wk : which == 2 ? Wv : Wo) + off;
    Wt = (which == 0 ? Wqt : which == 1 ? Wkt : which == 2 ? Wvt : Wot);
  } else if (bid < 2048) {
    const int r = bid - 1024;
    bx = r & 63; by = r >> 6; K = DMOD; N = DFFN;
    W = W1 + (size_t)layer * DMOD * DFFN; Wt = W1t;
  } else {
    const int r = bid - 2048;
    bx = r & 15; by = r >> 4; K = DFFN; N = DMOD;
    W = W2 + (size_t)layer * DMOD * DFFN; Wt = W2t;
  }
  const int n0 = bx * 64, k0 = by * 64;
  const int tx = threadIdx.x & 63, ty = threadIdx.x >> 6;
  #pragma unroll
  for (int i = 0; i < 16; i++) {
    int r = ty + 4 * i;
    tile[r][tx] = W[(size_t)(k0 + r) * N + n0 + tx];
  }
  __syncthreads();
  #pragma unroll
  for (int i = 0; i < 16; i++) {
    int rn = ty + 4 * i;
    Wt[(size_t)(n0 + rn) * K + k0 + tx] = f2bf(tile[tx][rn]);
  }
}

// ---------------- LayerNorm: one block per row; BF16IN selects input dtype ------
template<int BF16IN>
__global__ __launch_bounds__(256) void ln_kernel(
    const void* __restrict__ xin, const float* __restrict__ g,
    const float* __restrict__ bta, unsigned short* __restrict__ o16)
{
  const int row = blockIdx.x;
  const int t = threadIdx.x;
  float4 v;
  if (BF16IN) {
    ushort4 u = ((const ushort4*)((const unsigned short*)xin + (size_t)row * DMOD))[t];
    v.x = bf2f(u.x); v.y = bf2f(u.y); v.z = bf2f(u.z); v.w = bf2f(u.w);
  } else {
    v = ((const float4*)((const float*)xin + (size_t)row * DMOD))[t];
  }
  float s  = v.x + v.y + v.z + v.w;
  float s2 = v.x*v.x + v.y*v.y + v.z*v.z + v.w*v.w;
  #pragma unroll
  for (int off = 32; off > 0; off >>= 1) {
    s  += __shfl_down(s, off);
    s2 += __shfl_down(s2, off);
  }
  __shared__ float red[8];
  if ((t & 63) == 0) { red[(t >> 6) * 2] = s; red[(t >> 6) * 2 + 1] = s2; }
  __syncthreads();
  const float sum  = red[0] + red[2] + red[4] + red[6];
  const float sum2 = red[1] + red[3] + red[5] + red[7];
  const float mean = sum * (1.f / (float)DMOD);
  const float var  = sum2 * (1.f / (float)DMOD) - mean * mean;
  const float rstd = rsqrtf(var + 1e-6f);
  const float4 gg = ((const float4*)g)[t];
  const float4 bb = ((const float4*)bta)[t];
  ushort4 h;
  h.x = f2bf((v.x - mean) * rstd * gg.x + bb.x);
  h.y = f2bf((v.y - mean) * rstd * gg.y + bb.y);
  h.z = f2bf((v.z - mean) * rstd * gg.z + bb.z);
  h.w = f2bf((v.w - mean) * rstd * gg.w + bb.w);
  ((ushort4*)o16)[(size_t)row * 256 + t] = h;
}

// ---------------- GEMM 128x256, 8 waves, BK=64 single-buffer (ROUND-16 core) -----
// 64 KB LDS; epilogue uses 8 private wave slabs -> zero epilogue barriers.
// Swizzle for 128B rows: 16B-chunk idx (3b) ^ (row&7), both sides.
// launch_bounds(512,4): round-9 lesson — never raise min-waves blind.
// MODE 0: fused QKV via grid.z: z=0 Q (bias,*0.125,bf16), z=1 K (bias,bf16),
//         z=2 V (bias, bf16 V^T [b][ch][l]).  A = z?A1:A0.
// MODE 1: bias+gelu->bf16 (W1).
// MODE 4: bias + IN-PLACE bf16 add (Wo: outp += acc+bias, slab bounce + RMW).
// MODE 5: bias + res(bf16) -> f32 (final W2: out = acc + bias + bf2f(res16)).
// MODE 6: bias + res(bf16) -> bf16 (intermediate W2; slab bounce, coalesced).
template<int MODE>
__global__ __launch_bounds__(512, 4) void gemm128(
    const unsigned short* __restrict__ A0, const unsigned short* __restrict__ A1,
    const unsigned short* __restrict__ B0, const unsigned short* __restrict__ B1,
    const unsigned short* __restrict__ B2,
    const float* __restrict__ bias0, const float* __restrict__ bias1,
    const float* __restrict__ bias2, const void* __restrict__ resv,
    void* out0, void* out1, void* out2, int N, int K)
{
  __shared__ unsigned short Sh[32768];   // 64 KB: stage As[0,8192) Bs[8192,24576)
  unsigned short* As = Sh;               // 128 rows x 64 hw (128 B/row)
  unsigned short* Bs = Sh + 8192;        // 256 rows x 64 hw
  const int t = threadIdx.x;
  const int lane = t & 63, w = t >> 6;
  const int wm = w >> 2, wn = w & 3;     // 2(M) x 4(N) wave grid; wave owns 64x64
  const int g = lane >> 4, rm = lane & 15;

  // XCD-aware bijective remap over the whole (possibly 3D) grid
  const int gx = gridDim.x, gy = gridDim.y;
  const int nwg = gx * gy * gridDim.z;
  const int hid = (blockIdx.z * gy + blockIdx.y) * gx + blockIdx.x;
  const int wid = (hid & 7) * (nwg >> 3) + (hid >> 3);
  const int bx = wid % gx;
  const int rest = wid / gx;
  const int by = rest % gy;
  const int z  = rest / gy;              // 0 for 2D grids

  const unsigned short* A  = (MODE == 0 && z) ? A1 : A0;
  const unsigned short* Bt = (MODE == 0) ? (z == 0 ? B0 : z == 1 ? B1 : B2) : B0;
  const float* bias        = (MODE == 0) ? (z == 0 ? bias0 : z == 1 ? bias1 : bias2) : bias0;
  void* outp               = (MODE == 0) ? (z == 0 ? out0 : z == 1 ? out1 : out2) : out0;

  const size_t tm = (size_t)by * 128;
  const size_t tn = (size_t)bx * 256;

  // staging per K-tile: A 1024 16B-chunks (2/thread), B 2048 (4/thread).
  const int ia0 = t, ia1 = 512 + t;
  const int ra0 = ia0 >> 3, ra1 = ia1 >> 3;
  const int ca0 = 8 * ((ia0 & 7) ^ (ra0 & 7));
  const int ca1 = 8 * ((ia1 & 7) ^ (ra1 & 7));
  const int ib0 = t, ib1 = 512 + t, ib2 = 1024 + t, ib3 = 1536 + t;
  const int rb0 = ib0 >> 3, rb1 = ib1 >> 3, rb2 = ib2 >> 3, rb3 = ib3 >> 3;
  const int cb0 = 8 * ((ib0 & 7) ^ (rb0 & 7));
  const int cb1 = 8 * ((ib1 & 7) ^ (rb1 & 7));
  const int cb2 = 8 * ((ib2 & 7) ^ (rb2 & 7));
  const int cb3 = 8 * ((ib3 & 7) ^ (rb3 & 7));
  const unsigned short* Ab0 = A + (tm + ra0) * (size_t)K + ca0;
  const unsigned short* Ab1 = A + (tm + ra1) * (size_t)K + ca1;
  const unsigned short* Bb0 = Bt + (tn + rb0) * (size_t)K + cb0;
  const unsigned short* Bb1 = Bt + (tn + rb1) * (size_t)K + cb1;
  const unsigned short* Bb2 = Bt + (tn + rb2) * (size_t)K + cb2;
  const unsigned short* Bb3 = Bt + (tn + rb3) * (size_t)K + cb3;

  // swizzled fragment read offsets (bytes), kd=0; kd=1 is ^64
  int aoff[4], boff[4];
  #pragma unroll
  for (int fm = 0; fm < 4; fm++) {
    const int r = wm * 64 + fm * 16 + rm;
    aoff[fm] = r * 128 + ((g ^ (r & 7)) * 16);
  }
  #pragma unroll
  for (int fn = 0; fn < 4; fn++) {
    const int r = wn * 64 + fn * 16 + rm;
    boff[fn] = r * 128 + ((g ^ (r & 7)) * 16);
  }

  f32x4 acc[4][4];
  #pragma unroll
  for (int i = 0; i < 4; i++)
    #pragma unroll
    for (int j = 0; j < 4; j++)
      acc[i][j] = (f32x4){0.f, 0.f, 0.f, 0.f};

  const int nt = K >> 6;   // BK = 64
  for (int kt = 0; kt < nt; kt++) {
    const int k0 = kt * 64;
    GLOAD16(Ab0 + k0, &As[ia0 * 8]);
    GLOAD16(Ab1 + k0, &As[ia1 * 8]);
    GLOAD16(Bb0 + k0, &Bs[ib0 * 8]);
    GLOAD16(Bb1 + k0, &Bs[ib1 * 8]);
    GLOAD16(Bb2 + k0, &Bs[ib2 * 8]);
    GLOAD16(Bb3 + k0, &Bs[ib3 * 8]);
    __syncthreads();
    {
      short8 a[4], b[4];
      #pragma unroll
      for (int fm = 0; fm < 4; fm++) a[fm] = *(const short8*)((const char*)As + aoff[fm]);
      #pragma unroll
      for (int fn = 0; fn < 4; fn++) b[fn] = *(const short8*)((const char*)Bs + boff[fn]);
      #pragma unroll
      for (int fm = 0; fm < 4; fm++)
        #pragma unroll
        for (int fn = 0; fn < 4; fn++)
          acc[fm][fn] = MFMA16(a[fm], b[fn], acc[fm][fn]);
    }
    {
      short8 a[4], b[4];
      #pragma unroll
      for (int fm = 0; fm < 4; fm++) a[fm] = *(const short8*)((const char*)As + (aoff[fm] ^ 64));
      #pragma unroll
      for (int fn = 0; fn < 4; fn++) b[fn] = *(const short8*)((const char*)Bs + (boff[fn] ^ 64));
      #pragma unroll
      for (int fm = 0; fm < 4; fm++)
        #pragma unroll
        for (int fn = 0; fn < 4; fn++)
          acc[fm][fn] = MFMA16(a[fm], b[fn], acc[fm][fn]);
    }
    __syncthreads();
  }
  // After the final barrier all LDS reads are done; each wave uses its OWN
  // 8 KB slab (Sh + w*4096 hw) for bf16 bounces -> no epilogue barriers.

  if (MODE == 5) {
    const unsigned short* res16 = (const unsigned short*)resv;
    #pragma unroll
    for (int fn = 0; fn < 4; fn++) {
      const size_t gcol = tn + wn * 64 + fn * 16 + rm;
      const float bc = bias[gcol];
      #pragma unroll
      for (int fm = 0; fm < 4; fm++) {
        #pragma unroll
        for (int r = 0; r < 4; r++) {
          const size_t grow = tm + wm * 64 + fm * 16 + g * 4 + r;
          const size_t off = grow * (size_t)N + gcol;
          ((float*)outp)[off] = acc[fm][fn][r] + bc + bf2f(res16[off]);
        }
      }
    }
  } else if (MODE == 4 || MODE == 6) {
    // bf16 bounce + coalesced add: MODE 4 adds outp (in-place), MODE 6 adds res16
    const unsigned short* res16 = (MODE == 6) ? (const unsigned short*)resv : nullptr;
    unsigned short* eb = Sh + w * 4096;
    #pragma unroll
    for (int fn = 0; fn < 4; fn++) {
      const float bc = bias[tn + wn * 64 + fn * 16 + rm];
      #pragma unroll
      for (int fm = 0; fm < 4; fm++)
        #pragma unroll
        for (int r = 0; r < 4; r++) {
          const int lr = fm * 16 + g * 4 + r;
          const int lc = fn * 16 + rm;
          eb[lr * 64 + (lc ^ (g << 4))] = f2bf(acc[fm][fn][r] + bc);
        }
    }
    #pragma unroll
    for (int pass = 0; pass < 8; pass++) {
      const int lr = pass * 8 + (lane >> 3);
      const int lc8 = (lane & 7) * 8;
      const int q = (lr >> 2) & 3;
      short8 nv = *(const short8*)&eb[lr * 64 + (lc8 ^ (q << 4))];
      const size_t goff = (tm + wm * 64 + lr) * (size_t)N + tn + wn * 64 + lc8;
      unsigned short* gp = (unsigned short*)outp + goff;
      short8 ov = (MODE == 6) ? *(const short8*)(res16 + goff) : *(const short8*)gp;
      short8 rv;
      #pragma unroll
      for (int j = 0; j < 8; j++)
        rv[j] = (short)f2bf(bf2f((unsigned short)nv[j]) + bf2f((unsigned short)ov[j]));
      *(short8*)gp = rv;
    }
  } else if (MODE == 0) {
    unsigned short* eb = Sh + w * 4096;    // private slab
    if (z == 2) {
      // V^T slab [64 ch][64 tok]
      #pragma unroll
      for (int fn = 0; fn < 4; fn++) {
        const float bc = bias[tn + wn * 64 + fn * 16 + rm];
        #pragma unroll
        for (int fm = 0; fm < 4; fm++)
          #pragma unroll
          for (int r = 0; r < 4; r++) {
            const int tok = fm * 16 + g * 4 + r;
            const int ch  = fn * 16 + rm;
            eb[ch * 64 + (tok ^ ((ch & 7) << 3))] = f2bf(acc[fm][fn][r] + bc);
          }
      }
      const int tok0 = (int)tm + wm * 64;
      const int bb = tok0 >> 9, l0 = tok0 & 511;
      #pragma unroll
      for (int pass = 0; pass < 8; pass++) {
        const int ch = pass * 8 + (lane >> 3);
        const int t8 = (lane & 7) * 8;
        short8 vv = *(const short8*)&eb[ch * 64 + (t8 ^ ((ch & 7) << 3))];
        *(short8*)((unsigned short*)outp +
                   ((size_t)bb * 1024 + tn + wn * 64 + ch) * 512 + l0 + t8) = vv;
      }
    } else {
      // row-major slab [64 rows][64 cols]
      #pragma unroll
      for (int fn = 0; fn < 4; fn++) {
        const float bc = bias[tn + wn * 64 + fn * 16 + rm];
        #pragma unroll
        for (int fm = 0; fm < 4; fm++)
          #pragma unroll
          for (int r = 0; r < 4; r++) {
            float v = acc[fm][fn][r] + bc;
            if (z == 0) v *= 0.125f;
            const int lr = fm * 16 + g * 4 + r;
            const int lc = fn * 16 + rm;
            eb[lr * 64 + (lc ^ (g << 4))] = f2bf(v);
          }
      }
      #pragma unroll
      for (int pass = 0; pass < 8; pass++) {
        const int lr = pass * 8 + (lane >> 3);
        const int lc8 = (lane & 7) * 8;
        const int q = (lr >> 2) & 3;
        short8 vv = *(const short8*)&eb[lr * 64 + (lc8 ^ (q << 4))];
        *(short8*)((unsigned short*)outp +
                   (tm + wm * 64 + lr) * (size_t)N + tn + wn * 64 + lc8) = vv;
      }
    }
  } else {
    // MODE 1: gelu bf16 row-major, private slab
    unsigned short* eb = Sh + w * 4096;
    #pragma unroll
    for (int fn = 0; fn < 4; fn++) {
      const float bc = bias[tn + wn * 64 + fn * 16 + rm];
      #pragma unroll
      for (int fm = 0; fm < 4; fm++)
        #pragma unroll
        for (int r = 0; r < 4; r++) {
          const int lr = fm * 16 + g * 4 + r;
          const int lc = fn * 16 + rm;
          eb[lr * 64 + (lc ^ (g << 4))] = f2bf(gelu_f(acc[fm][fn][r] + bc));
        }
    }
    #pragma unroll
    for (int pass = 0; pass < 8; pass++) {
      const int lr = pass * 8 + (lane >> 3);
      const int lc8 = (lane & 7) * 8;
      const int q = (lr >> 2) & 3;
      short8 vv = *(const short8*)&eb[lr * 64 + (lc8 ^ (q << 4))];
      *(short8*)((unsigned short*)outp +
                 (tm + wm * 64 + lr) * (size_t)N + tn + wn * 64 + lc8) = vv;
    }
  }
}

// ---------------- MFMA flash attention: KVBLK=64, Q-region reuse (ROUND-14) -----
__global__ __launch_bounds__(256) void attn_mfma(
    const unsigned short* __restrict__ qb, const unsigned short* __restrict__ kb,
    const unsigned short* __restrict__ vt, unsigned short* __restrict__ ctx)
{
  __shared__ unsigned short Sh[8192];          // 16 KB: Q(128x64hw) -> K(64x64)|V(64x64)
  __shared__ unsigned short Ps[4][32 * 72];    // 18 KB
  unsigned short* Ks = Sh;
  unsigned short* Vs = Sh + 4096;
  const int t = threadIdx.x;
  const int lane = t & 63, w = t >> 6;
  const int g = lane >> 4, rm = lane & 15;
  const int qt = blockIdx.x, h = blockIdx.y, b = blockIdx.z;

  const unsigned short* qg = qb + ((size_t)(b * SEQ + qt * 128)) * DMOD + h * DHEAD;
  const unsigned short* kg = kb + ((size_t)(b * SEQ)) * DMOD + h * DHEAD;
  const unsigned short* vg = vt + ((size_t)(b * NHEAD + h)) * DHEAD * SEQ;  // [64][512]

  #pragma unroll
  for (int ii = 0; ii < 4; ii++) {
    const int i = ii * 256 + t;
    const int r = i >> 3, c = i & 7;
    const int bc = 16 * (c ^ (r & 7));
    GLOAD16(qg + (size_t)r * DMOD + (bc >> 1), Sh + (size_t)(ii * 256 + w * 64) * 8);
  }
  __syncthreads();

  short8 aq[2][2];
  #pragma unroll
  for (int fq = 0; fq < 2; fq++)
    #pragma unroll
    for (int kd = 0; kd < 2; kd++) {
      const int r = w * 32 + fq * 16 + rm;
      aq[fq][kd] = *(const short8*)((const char*)Sh + r * 128 + ((kd * 64 + g * 16) ^ ((r & 7) << 4)));
    }
  __syncthreads();   // all aq reads done before K/V staging overwrites Q region

  float mrow[2][4], lsum[2][4];
  f32x4 of[2][4];
  #pragma unroll
  for (int fq = 0; fq < 2; fq++) {
    #pragma unroll
    for (int j = 0; j < 4; j++) { mrow[fq][j] = -INFINITY; lsum[fq][j] = 0.f; }
    #pragma unroll
    for (int fd = 0; fd < 4; fd++) of[fq][fd] = (f32x4){0.f, 0.f, 0.f, 0.f};
  }

  for (int kt = 0; kt < SEQ / 64; kt++) {
    {
      const int i = t, r = i >> 3, c = i & 7;
      const int bc = 16 * (c ^ (r & 7));
      GLOAD16(kg + (size_t)(kt * 64 + r) * DMOD + (bc >> 1), Ks + (size_t)w * 512);
    }
    {
      const int i = 256 + t, r = i >> 3, c = i & 7;
      const int bc = 16 * (c ^ (r & 7));
      GLOAD16(kg + (size_t)(kt * 64 + r) * DMOD + (bc >> 1), Ks + 2048 + (size_t)w * 512);
    }
    {
      const int i = t, r = i >> 3, c = i & 7;
      const int bc = 16 * (c ^ (r & 7));
      GLOAD16(vg + (size_t)r * SEQ + kt * 64 + (bc >> 1), Vs + (size_t)w * 512);
    }
    {
      const int i = 256 + t, r = i >> 3, c = i & 7;
      const int bc = 16 * (c ^ (r & 7));
      GLOAD16(vg + (size_t)r * SEQ + kt * 64 + (bc >> 1), Vs + 2048 + (size_t)w * 512);
    }
    __syncthreads();

    f32x4 s[2][4];
    #pragma unroll
    for (int fq = 0; fq < 2; fq++)
      #pragma unroll
      for (int fk = 0; fk < 4; fk++) {
        f32x4 a = (f32x4){0.f, 0.f, 0.f, 0.f};
        #pragma unroll
        for (int kd = 0; kd < 2; kd++) {
          const int r = fk * 16 + rm;
          short8 bk = *(const short8*)((const char*)Ks + r * 128 + ((kd * 64 + g * 16) ^ ((r & 7) << 4)));
          a = MFMA16(aq[fq][kd], bk, a);
        }
        s[fq][fk] = a;
      }

    float pm[2][4];
    int grow = 0;
    #pragma unroll
    for (int fq = 0; fq < 2; fq++)
      #pragma unroll
      for (int j = 0; j < 4; j++) {
        float mx = fmaxf(fmaxf(s[fq][0][j], s[fq][1][j]), fmaxf(s[fq][2][j], s[fq][3][j]));
        #pragma unroll
        for (int mk = 1; mk < 16; mk <<= 1) mx = fmaxf(mx, __shfl_xor(mx, mk));
        pm[fq][j] = mx;
        grow |= (mx > mrow[fq][j] + 8.f);
      }
    if (__any(grow)) {
      #pragma unroll
      for (int fq = 0; fq < 2; fq++)
        #pragma unroll
        for (int j = 0; j < 4; j++) {
          const float mn = fmaxf(mrow[fq][j], pm[fq][j]);
          const float corr = __expf(mrow[fq][j] - mn);
          mrow[fq][j] = mn;
          lsum[fq][j] *= corr;
          #pragma unroll
          for (int fd = 0; fd < 4; fd++) of[fq][fd][j] *= corr;
        }
    }
    #pragma unroll
    for (int fq = 0; fq < 2; fq++)
      #pragma unroll
      for (int j = 0; j < 4; j++) {
        const int prow = (fq * 16 + g * 4 + j) * 72;
        float psum = 0.f;
        #pragma unroll
        for (int fk = 0; fk < 4; fk++) {
          const float p = __expf(s[fq][fk][j] - mrow[fq][j]);
          psum += p;
          Ps[w][prow + fk * 16 + rm] = f2bf(p);
        }
        lsum[fq][j] += psum;
      }

    #pragma unroll
    for (int fq = 0; fq < 2; fq++) {
      short8 pa0 = *(const short8*)&Ps[w][(fq * 16 + rm) * 72 + g * 8];
      short8 pa1 = *(const short8*)&Ps[w][(fq * 16 + rm) * 72 + 32 + g * 8];
      #pragma unroll
      for (int fd = 0; fd < 4; fd++) {
        const int r = fd * 16 + rm;
        const short8 vb0 = *(const short8*)((const char*)Vs + r * 128 + ((g * 16) ^ ((r & 7) << 4)));
        const short8 vb1 = *(const short8*)((const char*)Vs + r * 128 + ((64 + g * 16) ^ ((r & 7) << 4)));
        of[fq][fd] = MFMA16(pa0, vb0, of[fq][fd]);
        of[fq][fd] = MFMA16(pa1, vb1, of[fq][fd]);
      }
    }

    __syncthreads();
  }

  #pragma unroll
  for (int fq = 0; fq < 2; fq++)
    #pragma unroll
    for (int j = 0; j < 4; j++) {
      float ls = lsum[fq][j];
      #pragma unroll
      for (int mk = 1; mk < 16; mk <<= 1) ls += __shfl_xor(ls, mk);
      const float inv = 1.f / ls;
      const size_t q = (size_t)b * SEQ + qt * 128 + w * 32 + fq * 16 + g * 4 + j;
      #pragma unroll
      for (int fd = 0; fd < 4; fd++)
        ctx[q * DMOD + h * DHEAD + fd * 16 + rm] = f2bf(of[fq][fd][j] * inv);
    }
}

extern "C" void kernel_launch(void* const* d_in, const int* in_sizes, int n_in,
                              void* d_out, int out_size, void* d_ws, size_t ws_size,
                              hipStream_t stream) {
  const float* x_a   = (const float*)d_in[0];
  const float* x_b   = (const float*)d_in[1];
  const float* spk   = (const float*)d_in[2];
  const float* Wq    = (const float*)d_in[3];
  const float* bq    = (const float*)d_in[4];
  const float* Wk    = (const float*)d_in[5];
  const float* bk    = (const float*)d_in[6];
  const float* Wv    = (const float*)d_in[7];
  const float* bv    = (const float*)d_in[8];
  const float* Wo    = (const float*)d_in[9];
  const float* bo    = (const float*)d_in[10];
  const float* ln_g  = (const float*)d_in[11];
  const float* ln_b  = (const float*)d_in[12];
  const float* fln_g = (const float*)d_in[13];
  const float* fln_b = (const float*)d_in[14];
  const float* W1    = (const float*)d_in[15];
  const float* b1    = (const float*)d_in[16];
  const float* W2    = (const float*)d_in[17];
  const float* b2    = (const float*)d_in[18];
  float* out = (float*)d_out;           // f32 final output (written by layer-3 W2)

  char* ws = (char*)d_ws;
  size_t o = 0;
  auto give = [&](size_t bytes) { char* p = ws + o; o += (bytes + 255) & ~(size_t)255; return p; };
  const size_t ACT2 = (size_t)NTOK * DMOD * 2;   // 32 MB bf16 activation

  // qb,kb,vt,ctx contiguous (128 MB) -> `inter` aliases the span during FFN.
  unsigned short* qb16  = (unsigned short*)give(ACT2);
  unsigned short* kb16  = (unsigned short*)give(ACT2);
  unsigned short* vt16  = (unsigned short*)give(ACT2);       // V^T [b][h][d][l]
  unsigned short* ctx16 = (unsigned short*)give(ACT2);
  unsigned short* xa16  = (unsigned short*)give(ACT2);
  unsigned short* xbn16 = (unsigned short*)give(ACT2);       // XN / bf16 residual stream
  unsigned short* xn2   = (unsigned short*)give(ACT2);       // FFN-LN out AND bf16 master
  unsigned short* Wqt   = (unsigned short*)give((size_t)DMOD * DMOD * 2);
  unsigned short* Wkt   = (unsigned short*)give((size_t)DMOD * DMOD * 2);
  unsigned short* Wvt   = (unsigned short*)give((size_t)DMOD * DMOD * 2);
  unsigned short* Wot   = (unsigned short*)give((size_t)DMOD * DMOD * 2);
  unsigned short* W1t   = (unsigned short*)give((size_t)DMOD * DFFN * 2);
  unsigned short* W2t   = (unsigned short*)give((size_t)DMOD * DFFN * 2);
  float*          peb   = (float*)give((size_t)SEQ * DMOD * 4);
  unsigned short* inter = qb16;     // 128 MB span over qb16..ctx16 (dead during FFN)
  (void)ws_size; (void)in_sizes; (void)n_in; (void)out_size;

  const dim3 blk(256);
  const dim3 blk512(512);

  pe_kernel<<<dim3((SEQ * (DMOD / 2)) / 256), blk, 0, stream>>>(peb);
  const int nprep = (NTOK * DMOD / 4) / 256;
  prep_kernel<<<dim3(nprep, 1, 2), blk, 0, stream>>>(x_a, x_b, peb, spk, xa16, xbn16);

  const dim3 gQKV(DMOD / 256, NTOK / 128, 3);   // (4,128,3) = 1536 blocks
  const dim3 gWO (DMOD / 256, NTOK / 128);      // (4,128)   = 512
  const dim3 gW1 (DFFN / 256, NTOK / 128);      // (16,128)  = 2048
  const dim3 gW2 (DMOD / 256, NTOK / 128);      // (4,128)   = 512

  for (int i = 0; i < NLAY; i++) {
    wtrans_all<<<dim3(3072), blk, 0, stream>>>(Wq, Wk, Wv, Wo, W1, W2, i,
                                               Wqt, Wkt, Wvt, Wot, W1t, W2t);
    if (i != 0) {
      // XN = LN(bf16 master in xn2) -> xbn16; xn2 is then free for this layer's LN2
      ln_kernel<1><<<dim3(NTOK), blk, 0, stream>>>(xn2, ln_g + (size_t)i * DMOD, ln_b + (size_t)i * DMOD, xbn16);
    }
    gemm128<0><<<gQKV, blk512, 0, stream>>>(
        xbn16, xa16, Wqt, Wkt, Wvt,
        bq + (size_t)i * DMOD, bk + (size_t)i * DMOD, bv + (size_t)i * DMOD,
        nullptr, qb16, kb16, vt16, DMOD, DMOD);
    attn_mfma<<<dim3(SEQ / 128, NHEAD, BATCH), blk, 0, stream>>>(qb16, kb16, vt16, ctx16);
    // out_res (bf16) = ctx @ Wo + bo + XN   (in-place into xbn16)
    gemm128<4><<<gWO, blk512, 0, stream>>>(
        ctx16, nullptr, Wot, nullptr, nullptr,
        bo + (size_t)i * DMOD, nullptr, nullptr, nullptr, xbn16, nullptr, nullptr, DMOD, DMOD);
    // xn2 = LN(out_res)
    ln_kernel<1><<<dim3(NTOK), blk, 0, stream>>>(xbn16, fln_g + (size_t)i * DMOD, fln_b + (size_t)i * DMOD, xn2);
    gemm128<1><<<gW1, blk512, 0, stream>>>(
        xn2, nullptr, W1t, nullptr, nullptr,
        b1 + (size_t)i * DFFN, nullptr, nullptr, nullptr, inter, nullptr, nullptr, DFFN, DMOD);
    if (i == NLAY - 1) {
      // final: f32 output = inter @ W2 + b2 + out_res(bf16)
      gemm128<5><<<gW2, blk512, 0, stream>>>(
          inter, nullptr, W2t, nullptr, nullptr,
          b2 + (size_t)i * DMOD, nullptr, nullptr, xbn16, out, nullptr, nullptr, DMOD, DFFN);
    } else {
      // intermediate: bf16 master (xn2; dead after W1, re-read by next LN1)
      gemm128<6><<<gW2, blk512, 0, stream>>>(
          inter, nullptr, W2t, nullptr, nullptr,
          b2 + (size_t)i * DMOD, nullptr, nullptr, xbn16, xn2, nullptr, nullptr, DMOD, DFFN);
    }
  }
}